// Round 1
// baseline (890.583 us; speedup 1.0000x reference)
//
#include <hip/hip_runtime.h>
#include <math.h>

#define LSEQ 2048
#define DM   1024
#define EDIM 2048
#define RNK  64
#define NS   16
#define DBCW 96          // R + 2N
#define LC   32          // scan chunk length
#define NCH  (LSEQ / LC) // 64 chunks

// ---------------------------------------------------------------------------
// Generic f32 NT GEMM: C[M,N] = A[M,K] * B[N,K]^T  (+ optional softplus+bias)
// 64x64 tile, BK=16, 256 threads, 4x4 microtile.
// ---------------------------------------------------------------------------
#define BM 64
#define BN 64
#define BK 16

__global__ __launch_bounds__(256) void gemm_nt_f32(
    const float* __restrict__ A, int lda,
    const float* __restrict__ B, int ldb,
    float* __restrict__ C, int ldc,
    int M, int N, int K,
    const float* __restrict__ bias, int epi)
{
    __shared__ float As[BK][BM + 4];
    __shared__ float Bs[BK][BN + 4];
    const int bm = blockIdx.y * BM;
    const int bn = blockIdx.x * BN;
    const int tid = threadIdx.x;
    const int tx = tid & 15;     // 0..15 -> 4 cols each
    const int ty = tid >> 4;     // 0..15 -> 4 rows each
    const int kc = tid & 15;     // k within tile for loading
    const int r0 = tid >> 4;     // row base for loading

    float acc[4][4] = {};

    for (int k0 = 0; k0 < K; k0 += BK) {
        #pragma unroll
        for (int p = 0; p < 4; ++p) {
            int r = r0 + p * 16;
            int gr = bm + r;
            float v = 0.f;
            if (gr < M) v = A[(long)gr * lda + k0 + kc];
            As[kc][r] = v;
        }
        #pragma unroll
        for (int p = 0; p < 4; ++p) {
            int r = r0 + p * 16;
            int gr = bn + r;
            float v = 0.f;
            if (gr < N) v = B[(long)gr * ldb + k0 + kc];
            Bs[kc][r] = v;
        }
        __syncthreads();
        #pragma unroll
        for (int kk = 0; kk < BK; ++kk) {
            float4 a4 = *reinterpret_cast<const float4*>(&As[kk][ty * 4]);
            float4 b4 = *reinterpret_cast<const float4*>(&Bs[kk][tx * 4]);
            float av[4] = {a4.x, a4.y, a4.z, a4.w};
            float bv[4] = {b4.x, b4.y, b4.z, b4.w};
            #pragma unroll
            for (int i = 0; i < 4; ++i)
                #pragma unroll
                for (int j = 0; j < 4; ++j)
                    acc[i][j] = fmaf(av[i], bv[j], acc[i][j]);
        }
        __syncthreads();
    }

    #pragma unroll
    for (int i = 0; i < 4; ++i) {
        int r = bm + ty * 4 + i;
        if (r >= M) continue;
        #pragma unroll
        for (int j = 0; j < 4; ++j) {
            int c = bn + tx * 4 + j;
            if (c >= N) continue;
            float v = acc[i][j];
            if (epi == 1) {
                v += bias[c];
                // stable softplus: max(v,0) + log1p(exp(-|v|))
                v = fmaxf(v, 0.f) + log1pf(__expf(-fabsf(v)));
            }
            C[(long)r * ldc + c] = v;
        }
    }
}

// ---------------------------------------------------------------------------
// Depthwise causal conv (K=4) + bias + SiLU.
// xz: [L, 2*ED]; xr is the first ED columns. Output xrc: [L, ED].
// ---------------------------------------------------------------------------
__global__ __launch_bounds__(256) void conv_silu(
    const float* __restrict__ xz, const float* __restrict__ w,
    const float* __restrict__ b, float* __restrict__ xrc)
{
    int idx = blockIdx.x * 256 + threadIdx.x;   // l*ED + e
    int e = idx & (EDIM - 1);
    int l = idx >> 11;
    float acc = b[e];
    #pragma unroll
    for (int k = 0; k < 4; ++k) {
        int t = l - 3 + k;
        if (t >= 0) acc = fmaf(w[e * 4 + k], xz[(long)t * (2 * EDIM) + e], acc);
    }
    float s = acc / (1.f + __expf(-acc));       // silu
    xrc[(long)l * EDIM + e] = s;
}

// ---------------------------------------------------------------------------
// Selective scan, chunked 3-phase.
// Phase A: per (chunk, e): local scan from h=0, record decay product P and
//          local final h for each of the 16 states. Layout [c][n][e].
// ---------------------------------------------------------------------------
__global__ __launch_bounds__(256) void scan_phaseA(
    const float* __restrict__ delta, const float* __restrict__ xr,
    const float* __restrict__ dbc, const float* __restrict__ A_log,
    float* __restrict__ P, float* __restrict__ Hf)
{
    int g = blockIdx.x * 256 + threadIdx.x;
    int e = g & (EDIM - 1);
    int c = g >> 11;
    float Aa[NS], h[NS], Pp[NS];
    #pragma unroll
    for (int n = 0; n < NS; ++n) {
        Aa[n] = -__expf(A_log[e * NS + n]);
        h[n] = 0.f;
        Pp[n] = 1.f;
    }
    int t0 = c * LC;
    for (int t = t0; t < t0 + LC; ++t) {
        float d  = delta[(long)t * EDIM + e];
        float xv = xr[(long)t * EDIM + e];
        const float* bm = dbc + (long)t * DBCW + RNK;
        float dx = d * xv;
        #pragma unroll
        for (int n = 0; n < NS; ++n) {
            float a = __expf(d * Aa[n]);
            h[n] = fmaf(a, h[n], dx * bm[n]);
            Pp[n] *= a;
        }
    }
    #pragma unroll
    for (int n = 0; n < NS; ++n) {
        P [(long)(c * NS + n) * EDIM + e] = Pp[n];
        Hf[(long)(c * NS + n) * EDIM + e] = h[n];
    }
}

// Phase B: sequential combine across chunks per (e,n).
// Overwrites Hf[c] with the INCOMING prefix h for chunk c.
__global__ __launch_bounds__(256) void scan_phaseB(
    const float* __restrict__ P, float* __restrict__ Hf)
{
    int g = blockIdx.x * 256 + threadIdx.x;    // e + ED*n
    int e = g & (EDIM - 1);
    int n = g >> 11;                            // 0..15
    float h = 0.f;
    for (int c = 0; c < NCH; ++c) {
        long idx = (long)(c * NS + n) * EDIM + e;
        float p = P[idx];
        float f = Hf[idx];
        Hf[idx] = h;           // prefix in
        h = fmaf(p, h, f);
    }
}

// Phase C: redo local scan seeded with prefix, produce u = y * silu(z),
// written into the (dead) xr half of xz (row stride 2*ED).
__global__ __launch_bounds__(256) void scan_phaseC(
    const float* __restrict__ delta, const float* __restrict__ xr,
    const float* __restrict__ dbc, const float* __restrict__ A_log,
    const float* __restrict__ Hf, const float* __restrict__ Dp,
    float* __restrict__ xz)
{
    int g = blockIdx.x * 256 + threadIdx.x;
    int e = g & (EDIM - 1);
    int c = g >> 11;
    float Aa[NS], h[NS];
    #pragma unroll
    for (int n = 0; n < NS; ++n) {
        Aa[n] = -__expf(A_log[e * NS + n]);
        h[n] = Hf[(long)(c * NS + n) * EDIM + e];
    }
    float dD = Dp[e];
    int t0 = c * LC;
    for (int t = t0; t < t0 + LC; ++t) {
        float d  = delta[(long)t * EDIM + e];
        float xv = xr[(long)t * EDIM + e];
        const float* bm = dbc + (long)t * DBCW + RNK;
        const float* cm = dbc + (long)t * DBCW + RNK + NS;
        float dx = d * xv;
        float y = 0.f;
        #pragma unroll
        for (int n = 0; n < NS; ++n) {
            float a = __expf(d * Aa[n]);
            h[n] = fmaf(a, h[n], dx * bm[n]);
            y = fmaf(h[n], cm[n], y);
        }
        y = fmaf(dD, xv, y);
        float z = xz[(long)t * (2 * EDIM) + EDIM + e];
        float sz = z / (1.f + __expf(-z));
        xz[(long)t * (2 * EDIM) + e] = y * sz;   // u
    }
}

// ---------------------------------------------------------------------------
extern "C" void kernel_launch(void* const* d_in, const int* in_sizes, int n_in,
                              void* d_out, int out_size, void* d_ws, size_t ws_size,
                              hipStream_t stream) {
    const float* x         = (const float*)d_in[0];   // [1, L, DM]
    const float* in_proj_w = (const float*)d_in[1];   // [2*ED, DM]
    const float* conv_w    = (const float*)d_in[2];   // [ED, 1, 4]
    const float* conv_b    = (const float*)d_in[3];   // [ED]
    const float* x_proj_w  = (const float*)d_in[4];   // [96, ED]
    const float* dt_proj_w = (const float*)d_in[5];   // [ED, R]
    const float* dt_proj_b = (const float*)d_in[6];   // [ED]
    const float* A_log     = (const float*)d_in[7];   // [ED, N]
    const float* Dp        = (const float*)d_in[8];   // [ED]
    const float* out_proj_w= (const float*)d_in[9];   // [DM, ED]
    float* out = (float*)d_out;                       // [1, L, DM]

    float* ws    = (float*)d_ws;
    float* xz    = ws;                                 // [L, 2*ED]   8,388,608
    float* xrc   = xz   + (long)LSEQ * 2 * EDIM;       // [L, ED]     4,194,304
    float* dbc   = xrc  + (long)LSEQ * EDIM;           // [L, 96]       196,608
    float* delta = dbc  + (long)LSEQ * DBCW;           // [L, ED]     4,194,304
    float* P     = delta + (long)LSEQ * EDIM;          // [NCH, N, ED] 2,097,152
    float* Hf    = P    + (long)NCH * NS * EDIM;       // [NCH, N, ED] 2,097,152

    dim3 blk(256);

    // G1: xz = x @ in_proj_w^T    [2048,4096] k=1024
    gemm_nt_f32<<<dim3(2 * EDIM / BN, LSEQ / BM), blk, 0, stream>>>(
        x, DM, in_proj_w, DM, xz, 2 * EDIM, LSEQ, 2 * EDIM, DM, nullptr, 0);

    // conv + silu -> xrc
    conv_silu<<<(LSEQ * EDIM) / 256, blk, 0, stream>>>(xz, conv_w, conv_b, xrc);

    // G2: dbc = xrc @ x_proj_w^T  [2048,96] k=2048
    gemm_nt_f32<<<dim3((DBCW + BN - 1) / BN, LSEQ / BM), blk, 0, stream>>>(
        xrc, EDIM, x_proj_w, EDIM, dbc, DBCW, LSEQ, DBCW, EDIM, nullptr, 0);

    // G3: delta = softplus(delta_r @ dt_proj_w^T + b)  [2048,2048] k=64
    gemm_nt_f32<<<dim3(EDIM / BN, LSEQ / BM), blk, 0, stream>>>(
        dbc, DBCW, dt_proj_w, RNK, delta, EDIM, LSEQ, EDIM, RNK, dt_proj_b, 1);

    // scan
    scan_phaseA<<<(NCH * EDIM) / 256, blk, 0, stream>>>(delta, xrc, dbc, A_log, P, Hf);
    scan_phaseB<<<(EDIM * NS) / 256, blk, 0, stream>>>(P, Hf);
    scan_phaseC<<<(NCH * EDIM) / 256, blk, 0, stream>>>(delta, xrc, dbc, A_log, Hf, Dp, xz);

    // G4: out = u @ out_proj_w^T  [2048,1024] k=2048  (u lives in xz, lda=4096)
    gemm_nt_f32<<<dim3(DM / BN, LSEQ / BM), blk, 0, stream>>>(
        xz, 2 * EDIM, out_proj_w, EDIM, out, DM, LSEQ, DM, EDIM, nullptr, 0);
}

// Round 2
// 250.160 us; speedup vs baseline: 3.5601x; 3.5601x over previous
//
#include <hip/hip_runtime.h>
#include <math.h>

#define LSEQ 2048
#define DM   1024
#define EDIM 2048
#define RNK  64
#define NS   16
#define DBCW 96          // R + 2N
#define LC   32          // scan chunk length
#define NCH  (LSEQ / LC) // 64 chunks

typedef __attribute__((ext_vector_type(4))) float f32x4;
typedef __attribute__((ext_vector_type(8))) __bf16 bf16x8;

__device__ __forceinline__ ushort f2bf(float f) {
    unsigned u = __float_as_uint(f);
    unsigned r = (u + 0x7fffu + ((u >> 16) & 1u)) >> 16;
    return (ushort)r;
}

// ---------------------------------------------------------------------------
// f32 -> bf16 cast, contiguous, 4 elems/thread
// ---------------------------------------------------------------------------
__global__ __launch_bounds__(256) void cast_f32_bf16(
    const float* __restrict__ in, ushort* __restrict__ out)
{
    int idx = blockIdx.x * 256 + threadIdx.x;
    float4 v = *reinterpret_cast<const float4*>(&in[(long)idx * 4]);
    ushort4 o = make_ushort4(f2bf(v.x), f2bf(v.y), f2bf(v.z), f2bf(v.w));
    *reinterpret_cast<ushort4*>(&out[(long)idx * 4]) = o;
}

// u lives in xz (row stride 4096, first 2048 cols) -> ubf [2048][2048]
__global__ __launch_bounds__(256) void cast_u_bf16(
    const float* __restrict__ xz, ushort* __restrict__ ubf)
{
    int idx = blockIdx.x * 256 + threadIdx.x;   // 2048*512
    int row = idx >> 9;
    int c4 = (idx & 511) << 2;
    float4 v = *reinterpret_cast<const float4*>(&xz[(long)row * 4096 + c4]);
    ushort4 o = make_ushort4(f2bf(v.x), f2bf(v.y), f2bf(v.z), f2bf(v.w));
    *reinterpret_cast<ushort4*>(&ubf[(long)row * 2048 + c4]) = o;
}

// ---------------------------------------------------------------------------
// bf16 MFMA NT GEMM: C[M,N] = A[M,K] * B[N,K]^T, f32 out.
// 128x128 tile, BK=32, 4 waves (2x2 of 64x64), 16x16x32 bf16 MFMA.
// M%128==0, N%128==0, K%32==0 required.
// ---------------------------------------------------------------------------
__global__ __launch_bounds__(256) void gemm_nt_bf16(
    const ushort* __restrict__ A, const ushort* __restrict__ B,
    float* __restrict__ C, int ldc, int K, int grid_n)
{
    __shared__ ushort As[128 * 32];   // [row][k], 64B rows
    __shared__ ushort Bs[128 * 32];
    const int tid = threadIdx.x;
    const int wave = tid >> 6;
    const int lane = tid & 63;
    const int bm = (blockIdx.x / grid_n) * 128;
    const int bn = (blockIdx.x % grid_n) * 128;
    const int wm = (wave & 1) * 64;
    const int wn = (wave >> 1) * 64;

    f32x4 acc[4][4] = {};

    // staging decomposition for this thread
    const int offA = tid * 16;                 // bytes within 4096-B round
    const char* Ab = (const char*)A;
    const char* Bb = (const char*)B;
    char* AsB = (char*)As;
    char* BsB = (char*)Bs;

    for (int k0 = 0; k0 < K; k0 += 32) {
        __syncthreads();
        #pragma unroll
        for (int r = 0; r < 2; ++r) {
            int off = r * 4096 + offA;         // byte offset in 8192-B tile
            int row = off >> 6;                // 64B per row (32 bf16)
            int kb = off & 63;
            __builtin_amdgcn_global_load_lds(
                (const __attribute__((address_space(1))) void*)
                    (Ab + ((long)(bm + row) * K + k0) * 2 + kb),
                (__attribute__((address_space(3))) void*)
                    (AsB + r * 4096 + wave * 1024), 16, 0, 0);
            __builtin_amdgcn_global_load_lds(
                (const __attribute__((address_space(1))) void*)
                    (Bb + ((long)(bn + row) * K + k0) * 2 + kb),
                (__attribute__((address_space(3))) void*)
                    (BsB + r * 4096 + wave * 1024), 16, 0, 0);
        }
        __syncthreads();   // compiler emits vmcnt(0) drain here

        bf16x8 af[4], bf[4];
        #pragma unroll
        for (int i = 0; i < 4; ++i) {
            int ar = wm + i * 16 + (lane & 15);
            af[i] = *reinterpret_cast<const bf16x8*>(AsB + ar * 64 + (lane >> 4) * 16);
            int br = wn + i * 16 + (lane & 15);
            bf[i] = *reinterpret_cast<const bf16x8*>(BsB + br * 64 + (lane >> 4) * 16);
        }
        #pragma unroll
        for (int i = 0; i < 4; ++i)
            #pragma unroll
            for (int j = 0; j < 4; ++j)
                acc[i][j] = __builtin_amdgcn_mfma_f32_16x16x32_bf16(
                    af[i], bf[j], acc[i][j], 0, 0, 0);
    }

    // C/D layout: col = lane&15, row = (lane>>4)*4 + q   [m89-verified]
    #pragma unroll
    for (int i = 0; i < 4; ++i) {
        int row0 = bm + wm + i * 16 + (lane >> 4) * 4;
        #pragma unroll
        for (int j = 0; j < 4; ++j) {
            int col = bn + wn + j * 16 + (lane & 15);
            #pragma unroll
            for (int q = 0; q < 4; ++q)
                C[(long)(row0 + q) * ldc + col] = acc[i][j][q];
        }
    }
}

// ---------------------------------------------------------------------------
// f32 NT GEMM (used for G3): C[M,N] = A[M,K]*B[N,K]^T (+softplus+bias epi)
// ---------------------------------------------------------------------------
#define BM 64
#define BN 64
#define BK 16

__global__ __launch_bounds__(256) void gemm_nt_f32(
    const float* __restrict__ A, int lda,
    const float* __restrict__ B, int ldb,
    float* __restrict__ C, int ldc,
    int M, int N, int K,
    const float* __restrict__ bias, int epi)
{
    __shared__ float As[BK][BM + 4];
    __shared__ float Bs[BK][BN + 4];
    const int bm = blockIdx.y * BM;
    const int bn = blockIdx.x * BN;
    const int tid = threadIdx.x;
    const int tx = tid & 15;
    const int ty = tid >> 4;
    const int kc = tid & 15;
    const int r0 = tid >> 4;

    float acc[4][4] = {};

    for (int k0 = 0; k0 < K; k0 += BK) {
        #pragma unroll
        for (int p = 0; p < 4; ++p) {
            int r = r0 + p * 16;
            int gr = bm + r;
            float v = 0.f;
            if (gr < M) v = A[(long)gr * lda + k0 + kc];
            As[kc][r] = v;
        }
        #pragma unroll
        for (int p = 0; p < 4; ++p) {
            int r = r0 + p * 16;
            int gr = bn + r;
            float v = 0.f;
            if (gr < N) v = B[(long)gr * ldb + k0 + kc];
            Bs[kc][r] = v;
        }
        __syncthreads();
        #pragma unroll
        for (int kk = 0; kk < BK; ++kk) {
            float4 a4 = *reinterpret_cast<const float4*>(&As[kk][ty * 4]);
            float4 b4 = *reinterpret_cast<const float4*>(&Bs[kk][tx * 4]);
            float av[4] = {a4.x, a4.y, a4.z, a4.w};
            float bv[4] = {b4.x, b4.y, b4.z, b4.w};
            #pragma unroll
            for (int i = 0; i < 4; ++i)
                #pragma unroll
                for (int j = 0; j < 4; ++j)
                    acc[i][j] = fmaf(av[i], bv[j], acc[i][j]);
        }
        __syncthreads();
    }

    #pragma unroll
    for (int i = 0; i < 4; ++i) {
        int r = bm + ty * 4 + i;
        if (r >= M) continue;
        #pragma unroll
        for (int j = 0; j < 4; ++j) {
            int c = bn + tx * 4 + j;
            if (c >= N) continue;
            float v = acc[i][j];
            if (epi == 1) {
                v += bias[c];
                v = fmaxf(v, 0.f) + log1pf(__expf(-fabsf(v)));
            }
            C[(long)r * ldc + c] = v;
        }
    }
}

// ---------------------------------------------------------------------------
// G2 split-K: dbc_partial[kch][2048][96] = xrc[:, kch*256:+256] @ x_proj_w^T
// ---------------------------------------------------------------------------
__global__ __launch_bounds__(256) void gemm2_splitk(
    const float* __restrict__ A,   // xrc [2048][2048]
    const float* __restrict__ B,   // x_proj_w [96][2048]
    float* __restrict__ Pb)        // [8][2048][96]
{
    __shared__ float As[16][64 + 4];
    __shared__ float Bs[16][96 + 4];
    const int kch = blockIdx.x;    // 0..7
    const int mt  = blockIdx.y;    // 0..31
    const int tid = threadIdx.x;
    const int kc = tid & 15, r0 = tid >> 4;
    const int tx = tid & 15, ty = tid >> 4;
    float acc[4][6] = {};
    const int kbase = kch * 256;

    for (int k0 = 0; k0 < 256; k0 += 16) {
        #pragma unroll
        for (int p = 0; p < 4; ++p) {
            int r = r0 + p * 16;
            As[kc][r] = A[(long)(mt * 64 + r) * EDIM + kbase + k0 + kc];
        }
        #pragma unroll
        for (int p = 0; p < 6; ++p) {
            int r = r0 + p * 16;
            Bs[kc][r] = B[(long)r * EDIM + kbase + k0 + kc];
        }
        __syncthreads();
        #pragma unroll
        for (int kk = 0; kk < 16; ++kk) {
            float av[4], bv[6];
            #pragma unroll
            for (int i = 0; i < 4; ++i) av[i] = As[kk][ty * 4 + i];
            #pragma unroll
            for (int j = 0; j < 6; ++j) bv[j] = Bs[kk][tx * 6 + j];
            #pragma unroll
            for (int i = 0; i < 4; ++i)
                #pragma unroll
                for (int j = 0; j < 6; ++j)
                    acc[i][j] = fmaf(av[i], bv[j], acc[i][j]);
        }
        __syncthreads();
    }
    float* out = Pb + ((long)kch * LSEQ + mt * 64) * DBCW;
    #pragma unroll
    for (int i = 0; i < 4; ++i)
        #pragma unroll
        for (int j = 0; j < 6; ++j)
            out[(long)(ty * 4 + i) * DBCW + tx * 6 + j] = acc[i][j];
}

__global__ __launch_bounds__(256) void gemm2_reduce(
    const float* __restrict__ Pb, float* __restrict__ dbc)
{
    int idx = blockIdx.x * 256 + threadIdx.x;   // 2048*96
    float s = 0.f;
    #pragma unroll
    for (int c = 0; c < 8; ++c) s += Pb[(long)c * LSEQ * DBCW + idx];
    dbc[idx] = s;
}

// ---------------------------------------------------------------------------
// Depthwise causal conv (K=4) + bias + SiLU
// ---------------------------------------------------------------------------
__global__ __launch_bounds__(256) void conv_silu(
    const float* __restrict__ xz, const float* __restrict__ w,
    const float* __restrict__ b, float* __restrict__ xrc)
{
    int idx = blockIdx.x * 256 + threadIdx.x;
    int e = idx & (EDIM - 1);
    int l = idx >> 11;
    float acc = b[e];
    #pragma unroll
    for (int k = 0; k < 4; ++k) {
        int t = l - 3 + k;
        if (t >= 0) acc = fmaf(w[e * 4 + k], xz[(long)t * (2 * EDIM) + e], acc);
    }
    float s = acc / (1.f + __expf(-acc));
    xrc[(long)l * EDIM + e] = s;
}

// ---------------------------------------------------------------------------
// Selective scan, chunked 3-phase
// ---------------------------------------------------------------------------
__global__ __launch_bounds__(256) void scan_phaseA(
    const float* __restrict__ delta, const float* __restrict__ xr,
    const float* __restrict__ dbc, const float* __restrict__ A_log,
    float* __restrict__ P, float* __restrict__ Hf)
{
    int g = blockIdx.x * 256 + threadIdx.x;
    int e = g & (EDIM - 1);
    int c = g >> 11;
    float Aa[NS], h[NS], Pp[NS];
    #pragma unroll
    for (int n = 0; n < NS; ++n) {
        Aa[n] = -__expf(A_log[e * NS + n]);
        h[n] = 0.f;
        Pp[n] = 1.f;
    }
    int t0 = c * LC;
    for (int t = t0; t < t0 + LC; ++t) {
        float d  = delta[(long)t * EDIM + e];
        float xv = xr[(long)t * EDIM + e];
        const float* bm = dbc + (long)t * DBCW + RNK;
        float dx = d * xv;
        #pragma unroll
        for (int n = 0; n < NS; ++n) {
            float a = __expf(d * Aa[n]);
            h[n] = fmaf(a, h[n], dx * bm[n]);
            Pp[n] *= a;
        }
    }
    #pragma unroll
    for (int n = 0; n < NS; ++n) {
        P [(long)(c * NS + n) * EDIM + e] = Pp[n];
        Hf[(long)(c * NS + n) * EDIM + e] = h[n];
    }
}

__global__ __launch_bounds__(256) void scan_phaseB(
    const float* __restrict__ P, float* __restrict__ Hf)
{
    int g = blockIdx.x * 256 + threadIdx.x;
    int e = g & (EDIM - 1);
    int n = g >> 11;
    float h = 0.f;
    for (int c = 0; c < NCH; ++c) {
        long idx = (long)(c * NS + n) * EDIM + e;
        float p = P[idx];
        float f = Hf[idx];
        Hf[idx] = h;
        h = fmaf(p, h, f);
    }
}

__global__ __launch_bounds__(256) void scan_phaseC(
    const float* __restrict__ delta, const float* __restrict__ xr,
    const float* __restrict__ dbc, const float* __restrict__ A_log,
    const float* __restrict__ Hf, const float* __restrict__ Dp,
    float* __restrict__ xz)
{
    int g = blockIdx.x * 256 + threadIdx.x;
    int e = g & (EDIM - 1);
    int c = g >> 11;
    float Aa[NS], h[NS];
    #pragma unroll
    for (int n = 0; n < NS; ++n) {
        Aa[n] = -__expf(A_log[e * NS + n]);
        h[n] = Hf[(long)(c * NS + n) * EDIM + e];
    }
    float dD = Dp[e];
    int t0 = c * LC;
    for (int t = t0; t < t0 + LC; ++t) {
        float d  = delta[(long)t * EDIM + e];
        float xv = xr[(long)t * EDIM + e];
        const float* bm = dbc + (long)t * DBCW + RNK;
        const float* cm = dbc + (long)t * DBCW + RNK + NS;
        float dx = d * xv;
        float y = 0.f;
        #pragma unroll
        for (int n = 0; n < NS; ++n) {
            float a = __expf(d * Aa[n]);
            h[n] = fmaf(a, h[n], dx * bm[n]);
            y = fmaf(h[n], cm[n], y);
        }
        y = fmaf(dD, xv, y);
        float z = xz[(long)t * (2 * EDIM) + EDIM + e];
        float sz = z / (1.f + __expf(-z));
        xz[(long)t * (2 * EDIM) + e] = y * sz;   // u
    }
}

// ---------------------------------------------------------------------------
extern "C" void kernel_launch(void* const* d_in, const int* in_sizes, int n_in,
                              void* d_out, int out_size, void* d_ws, size_t ws_size,
                              hipStream_t stream) {
    const float* x         = (const float*)d_in[0];
    const float* in_proj_w = (const float*)d_in[1];
    const float* conv_w    = (const float*)d_in[2];
    const float* conv_b    = (const float*)d_in[3];
    const float* x_proj_w  = (const float*)d_in[4];
    const float* dt_proj_w = (const float*)d_in[5];
    const float* dt_proj_b = (const float*)d_in[6];
    const float* A_log     = (const float*)d_in[7];
    const float* Dp        = (const float*)d_in[8];
    const float* out_proj_w= (const float*)d_in[9];
    float* out = (float*)d_out;

    float* ws    = (float*)d_ws;
    float* xz    = ws;                                 // [L, 2*ED]    8,388,608 f32
    float* xrc   = xz   + (long)LSEQ * 2 * EDIM;       // [L, ED]      4,194,304
    float* dbc   = xrc  + (long)LSEQ * EDIM;           // [L, 96]        196,608
    float* delta = dbc  + (long)LSEQ * DBCW;           // [L, ED]      4,194,304
    float* shared= delta + (long)LSEQ * EDIM;          // 4,194,304 f32 shared region

    // overlays
    float* Pbuf  = delta;                              // [8][2048][96] (pre-G3)
    float* P     = shared;                             // [NCH,N,ED] 2,097,152
    float* Hf    = shared + (long)NCH * NS * EDIM;     // [NCH,N,ED] 2,097,152
    ushort* xbf  = (ushort*)shared;                    // [2048][1024]  (pre-scan)
    ushort* w1bf = (ushort*)(shared + (long)LSEQ * DM / 2);  // [4096][1024]
    ushort* ubf  = (ushort*)shared;                    // [2048][2048]  (post-scan)
    ushort* w4bf = (ushort*)(shared + (long)LSEQ * EDIM / 2);// [1024][2048]

    dim3 blk(256);

    // casts for G1
    cast_f32_bf16<<<(LSEQ * DM) / 1024, blk, 0, stream>>>(x, xbf);
    cast_f32_bf16<<<(2 * EDIM * DM) / 1024, blk, 0, stream>>>(in_proj_w, w1bf);

    // G1: xz = x @ in_proj_w^T   [2048,4096] k=1024   (bf16 MFMA)
    gemm_nt_bf16<<<(LSEQ / 128) * (4 * EDIM / 256), blk, 0, stream>>>(
        xbf, w1bf, xz, 2 * EDIM, DM, 2 * EDIM / 128);

    // conv + silu -> xrc
    conv_silu<<<(LSEQ * EDIM) / 256, blk, 0, stream>>>(xz, conv_w, conv_b, xrc);

    // G2: dbc = xrc @ x_proj_w^T  [2048,96] k=2048  (split-K x8)
    gemm2_splitk<<<dim3(8, LSEQ / 64), blk, 0, stream>>>(xrc, x_proj_w, Pbuf);
    gemm2_reduce<<<(LSEQ * DBCW) / 256, blk, 0, stream>>>(Pbuf, dbc);

    // G3: delta = softplus(delta_r @ dt_proj_w^T + b)  [2048,2048] k=64
    gemm_nt_f32<<<dim3(EDIM / BN, LSEQ / BM), blk, 0, stream>>>(
        dbc, DBCW, dt_proj_w, RNK, delta, EDIM, LSEQ, EDIM, RNK, dt_proj_b, 1);

    // scan
    scan_phaseA<<<(NCH * EDIM) / 256, blk, 0, stream>>>(delta, xrc, dbc, A_log, P, Hf);
    scan_phaseB<<<(EDIM * NS) / 256, blk, 0, stream>>>(P, Hf);
    scan_phaseC<<<(NCH * EDIM) / 256, blk, 0, stream>>>(delta, xrc, dbc, A_log, Hf, Dp, xz);

    // casts for G4 (u in xz, stride 4096)
    cast_u_bf16<<<(LSEQ * EDIM) / 1024, blk, 0, stream>>>(xz, ubf);
    cast_f32_bf16<<<(DM * EDIM) / 1024, blk, 0, stream>>>(out_proj_w, w4bf);

    // G4: out = u @ out_proj_w^T  [2048,1024] k=2048  (bf16 MFMA)
    gemm_nt_bf16<<<(LSEQ / 128) * (DM / 128), blk, 0, stream>>>(
        ubf, w4bf, out, DM, EDIM, DM / 128);
}

// Round 3
// 208.481 us; speedup vs baseline: 4.2718x; 1.1999x over previous
//
#include <hip/hip_runtime.h>
#include <math.h>

#define LSEQ 2048
#define DM   1024
#define EDIM 2048
#define RNK  64
#define NS   16
#define DBCW 96          // R + 2N
#define LC   32          // scan chunk length
#define NCH  (LSEQ / LC) // 64 chunks

typedef __attribute__((ext_vector_type(4))) float f32x4;
typedef __attribute__((ext_vector_type(8))) __bf16 bf16x8;

__device__ __forceinline__ ushort f2bf(float f) {
    unsigned u = __float_as_uint(f);
    unsigned r = (u + 0x7fffu + ((u >> 16) & 1u)) >> 16;
    return (ushort)r;
}

// ---------------------------------------------------------------------------
// Fused f32->bf16 casts: x (2M) -> xbf, in_proj_w (4M) -> w1bf,
// out_proj_w (2M) -> w4bf. 4 elems/thread.
// ---------------------------------------------------------------------------
__global__ __launch_bounds__(256) void cast_all(
    const float* __restrict__ x, const float* __restrict__ w1,
    const float* __restrict__ w4,
    ushort* __restrict__ xbf, ushort* __restrict__ w1bf,
    ushort* __restrict__ w4bf)
{
    long idx4 = ((long)blockIdx.x * 256 + threadIdx.x) * 4;
    const float* src;
    ushort* dst;
    long rel;
    if (idx4 < 2097152)       { src = x;  dst = xbf;  rel = idx4; }
    else if (idx4 < 6291456)  { src = w1; dst = w1bf; rel = idx4 - 2097152; }
    else                      { src = w4; dst = w4bf; rel = idx4 - 6291456; }
    float4 v = *reinterpret_cast<const float4*>(&src[rel]);
    ushort4 o = make_ushort4(f2bf(v.x), f2bf(v.y), f2bf(v.z), f2bf(v.w));
    *reinterpret_cast<ushort4*>(&dst[rel]) = o;
}

// ---------------------------------------------------------------------------
// bf16 MFMA NT GEMM: C = A[M,K]*B[N,K]^T, f32 out. 128x128 tile, BK=32,
// 4 waves (2x2 of 64x64), 16x16x32 MFMA. Supports split-K (blocks_per_k)
// and a column-split dual output (C0 for col<csplit, C1 otherwise).
// ---------------------------------------------------------------------------
__global__ __launch_bounds__(256) void gemm_nt_bf16(
    const ushort* __restrict__ A, int lda,
    const ushort* __restrict__ B, int ldb,
    float* __restrict__ C0, float* __restrict__ C1, int csplit, int ldc,
    long cplane, int klen, int grid_n, int blocks_per_k)
{
    __shared__ ushort As[128 * 32];   // [row][32 bf16 = 64B rows], linear
    __shared__ ushort Bs[128 * 32];
    const int tid = threadIdx.x;
    const int wave = tid >> 6;
    const int lane = tid & 63;
    const int kch = blockIdx.x / blocks_per_k;
    const int rem = blockIdx.x % blocks_per_k;
    const int bm = (rem / grid_n) * 128;
    const int bn = (rem % grid_n) * 128;
    const int wm = (wave & 1) * 64;
    const int wn = (wave >> 1) * 64;
    const int koff = kch * klen;
    C0 += (long)kch * cplane;

    f32x4 acc[4][4] = {};

    const int offT = tid * 16;                 // byte offset within 4096-B round
    const char* Ab = (const char*)A;
    const char* Bb = (const char*)B;
    char* AsB = (char*)As;
    char* BsB = (char*)Bs;

    for (int k0 = 0; k0 < klen; k0 += 32) {
        __syncthreads();
        #pragma unroll
        for (int r = 0; r < 2; ++r) {
            int off = r * 4096 + offT;         // byte offset in 8192-B tile
            int row = off >> 6;
            int kb = off & 63;
            __builtin_amdgcn_global_load_lds(
                (const __attribute__((address_space(1))) void*)
                    (Ab + ((long)(bm + row) * lda + koff + k0) * 2 + kb),
                (__attribute__((address_space(3))) void*)
                    (AsB + r * 4096 + wave * 1024), 16, 0, 0);
            __builtin_amdgcn_global_load_lds(
                (const __attribute__((address_space(1))) void*)
                    (Bb + ((long)(bn + row) * ldb + koff + k0) * 2 + kb),
                (__attribute__((address_space(3))) void*)
                    (BsB + r * 4096 + wave * 1024), 16, 0, 0);
        }
        __syncthreads();

        bf16x8 af[4], bfr[4];
        #pragma unroll
        for (int i = 0; i < 4; ++i) {
            int ar = wm + i * 16 + (lane & 15);
            af[i]  = *reinterpret_cast<const bf16x8*>(AsB + ar * 64 + (lane >> 4) * 16);
            int br = wn + i * 16 + (lane & 15);
            bfr[i] = *reinterpret_cast<const bf16x8*>(BsB + br * 64 + (lane >> 4) * 16);
        }
        #pragma unroll
        for (int i = 0; i < 4; ++i)
            #pragma unroll
            for (int j = 0; j < 4; ++j)
                acc[i][j] = __builtin_amdgcn_mfma_f32_16x16x32_bf16(
                    af[i], bfr[j], acc[i][j], 0, 0, 0);
    }

    // C/D layout: col = lane&15, row = (lane>>4)*4 + q
    #pragma unroll
    for (int i = 0; i < 4; ++i) {
        int row0 = bm + wm + i * 16 + (lane >> 4) * 4;
        #pragma unroll
        for (int j = 0; j < 4; ++j) {
            int col = bn + wn + j * 16 + (lane & 15);
            float* Cp;
            int cc;
            if (col < csplit) { Cp = C0; cc = col; }
            else              { Cp = C1; cc = col - csplit; }
            #pragma unroll
            for (int q = 0; q < 4; ++q)
                Cp[(long)(row0 + q) * ldc + cc] = acc[i][j][q];
        }
    }
}

// G4 reduce: out = Gp[0] + Gp[1], float4
__global__ __launch_bounds__(256) void g4_reduce(
    const float* __restrict__ Gp, float* __restrict__ out)
{
    long i4 = ((long)blockIdx.x * 256 + threadIdx.x) * 4;
    float4 a = *reinterpret_cast<const float4*>(&Gp[i4]);
    float4 b = *reinterpret_cast<const float4*>(&Gp[2097152 + i4]);
    float4 o = make_float4(a.x + b.x, a.y + b.y, a.z + b.z, a.w + b.w);
    *reinterpret_cast<float4*>(&out[i4]) = o;
}

// ---------------------------------------------------------------------------
// f32 NT GEMM (G3): C[M,N] = A[M,K]*B[N,K]^T (+softplus+bias epi)
// ---------------------------------------------------------------------------
#define BM 64
#define BN 64
#define BK 16

__global__ __launch_bounds__(256) void gemm_nt_f32(
    const float* __restrict__ A, int lda,
    const float* __restrict__ B, int ldb,
    float* __restrict__ C, int ldc,
    int M, int N, int K,
    const float* __restrict__ bias, int epi)
{
    __shared__ float As[BK][BM + 4];
    __shared__ float Bs[BK][BN + 4];
    const int bm = blockIdx.y * BM;
    const int bn = blockIdx.x * BN;
    const int tid = threadIdx.x;
    const int tx = tid & 15;
    const int ty = tid >> 4;
    const int kc = tid & 15;
    const int r0 = tid >> 4;

    float acc[4][4] = {};

    for (int k0 = 0; k0 < K; k0 += BK) {
        #pragma unroll
        for (int p = 0; p < 4; ++p) {
            int r = r0 + p * 16;
            As[kc][r] = A[(long)(bm + r) * lda + k0 + kc];
        }
        #pragma unroll
        for (int p = 0; p < 4; ++p) {
            int r = r0 + p * 16;
            Bs[kc][r] = B[(long)(bn + r) * ldb + k0 + kc];
        }
        __syncthreads();
        #pragma unroll
        for (int kk = 0; kk < BK; ++kk) {
            float4 a4 = *reinterpret_cast<const float4*>(&As[kk][ty * 4]);
            float4 b4 = *reinterpret_cast<const float4*>(&Bs[kk][tx * 4]);
            float av[4] = {a4.x, a4.y, a4.z, a4.w};
            float bv[4] = {b4.x, b4.y, b4.z, b4.w};
            #pragma unroll
            for (int i = 0; i < 4; ++i)
                #pragma unroll
                for (int j = 0; j < 4; ++j)
                    acc[i][j] = fmaf(av[i], bv[j], acc[i][j]);
        }
        __syncthreads();
    }

    #pragma unroll
    for (int i = 0; i < 4; ++i) {
        int r = bm + ty * 4 + i;
        #pragma unroll
        for (int j = 0; j < 4; ++j) {
            int c = bn + tx * 4 + j;
            float v = acc[i][j];
            if (epi == 1) {
                v += bias[c];
                v = fmaxf(v, 0.f) + log1pf(__expf(-fabsf(v)));
            }
            C[(long)r * ldc + c] = v;
        }
    }
}

// ---------------------------------------------------------------------------
// G2 split-K x16: Pb[kch][2048][96] = xrc[:, kch*128:+128] @ x_proj_w^T
// 32-row tiles -> grid (16, 64) = 1024 blocks.
// ---------------------------------------------------------------------------
__global__ __launch_bounds__(256) void gemm2_splitk(
    const float* __restrict__ A,   // xrc [2048][2048]
    const float* __restrict__ B,   // x_proj_w [96][2048]
    float* __restrict__ Pb)        // [16][2048][96]
{
    __shared__ float As[16][33];
    __shared__ float Bs[16][97];
    const int kch = blockIdx.x;    // 0..15
    const int mt  = blockIdx.y;    // 0..63
    const int tid = threadIdx.x;
    const int kc = tid & 15, r0 = tid >> 4;
    const int tx = tid & 15, ty = tid >> 4;
    float acc[2][6] = {};
    const int kbase = kch * 128;

    for (int k0 = 0; k0 < 128; k0 += 16) {
        #pragma unroll
        for (int p = 0; p < 2; ++p) {
            int r = r0 + p * 16;
            As[kc][r] = A[(long)(mt * 32 + r) * EDIM + kbase + k0 + kc];
        }
        #pragma unroll
        for (int p = 0; p < 6; ++p) {
            int r = r0 + p * 16;
            Bs[kc][r] = B[(long)r * EDIM + kbase + k0 + kc];
        }
        __syncthreads();
        #pragma unroll
        for (int kk = 0; kk < 16; ++kk) {
            float av[2], bv[6];
            #pragma unroll
            for (int i = 0; i < 2; ++i) av[i] = As[kk][ty * 2 + i];
            #pragma unroll
            for (int j = 0; j < 6; ++j) bv[j] = Bs[kk][tx * 6 + j];
            #pragma unroll
            for (int i = 0; i < 2; ++i)
                #pragma unroll
                for (int j = 0; j < 6; ++j)
                    acc[i][j] = fmaf(av[i], bv[j], acc[i][j]);
        }
        __syncthreads();
    }
    #pragma unroll
    for (int i = 0; i < 2; ++i)
        #pragma unroll
        for (int j = 0; j < 6; ++j)
            Pb[((long)kch * LSEQ + mt * 32 + ty * 2 + i) * DBCW + tx * 6 + j] = acc[i][j];
}

__global__ __launch_bounds__(256) void gemm2_reduce(
    const float* __restrict__ Pb, float* __restrict__ dbc)
{
    int idx = blockIdx.x * 256 + threadIdx.x;   // 2048*96
    float s = 0.f;
    #pragma unroll
    for (int c = 0; c < 16; ++c) s += Pb[(long)c * LSEQ * DBCW + idx];
    dbc[idx] = s;
}

// ---------------------------------------------------------------------------
// Depthwise causal conv (K=4) + bias + SiLU. Planar in/out, float4.
// ---------------------------------------------------------------------------
__global__ __launch_bounds__(256) void conv_silu(
    const float* __restrict__ xr, const float* __restrict__ w,
    const float* __restrict__ b, float* __restrict__ xrc)
{
    int idx = blockIdx.x * 256 + threadIdx.x;   // l*512 + e4
    int l = idx >> 9;
    int e4 = (idx & 511) << 2;
    float4 zero = make_float4(0.f, 0.f, 0.f, 0.f);
    float4 r0 = (l >= 3) ? *reinterpret_cast<const float4*>(&xr[(long)(l - 3) * EDIM + e4]) : zero;
    float4 r1 = (l >= 2) ? *reinterpret_cast<const float4*>(&xr[(long)(l - 2) * EDIM + e4]) : zero;
    float4 r2 = (l >= 1) ? *reinterpret_cast<const float4*>(&xr[(long)(l - 1) * EDIM + e4]) : zero;
    float4 r3 = *reinterpret_cast<const float4*>(&xr[(long)l * EDIM + e4]);
    float4 bb = *reinterpret_cast<const float4*>(&b[e4]);
    float rr0[4] = {r0.x, r0.y, r0.z, r0.w};
    float rr1[4] = {r1.x, r1.y, r1.z, r1.w};
    float rr2[4] = {r2.x, r2.y, r2.z, r2.w};
    float rr3[4] = {r3.x, r3.y, r3.z, r3.w};
    float bbv[4] = {bb.x, bb.y, bb.z, bb.w};
    float o[4];
    #pragma unroll
    for (int j = 0; j < 4; ++j) {
        float4 wj = *reinterpret_cast<const float4*>(&w[(e4 + j) * 4]);
        float acc = bbv[j];
        acc = fmaf(wj.x, rr0[j], acc);
        acc = fmaf(wj.y, rr1[j], acc);
        acc = fmaf(wj.z, rr2[j], acc);
        acc = fmaf(wj.w, rr3[j], acc);
        o[j] = acc / (1.f + __expf(-acc));
    }
    *reinterpret_cast<float4*>(&xrc[(long)l * EDIM + e4]) =
        make_float4(o[0], o[1], o[2], o[3]);
}

// ---------------------------------------------------------------------------
// Selective scan, chunked 3-phase
// ---------------------------------------------------------------------------
__global__ __launch_bounds__(256) void scan_phaseA(
    const float* __restrict__ delta, const float* __restrict__ xr,
    const float* __restrict__ dbc, const float* __restrict__ A_log,
    float* __restrict__ P, float* __restrict__ Hf)
{
    int g = blockIdx.x * 256 + threadIdx.x;
    int e = g & (EDIM - 1);
    int c = g >> 11;
    float Aa[NS], h[NS], Pp[NS];
    #pragma unroll
    for (int n = 0; n < NS; ++n) {
        Aa[n] = -__expf(A_log[e * NS + n]);
        h[n] = 0.f;
        Pp[n] = 1.f;
    }
    int t0 = c * LC;
    for (int t = t0; t < t0 + LC; ++t) {
        float d  = delta[(long)t * EDIM + e];
        float xv = xr[(long)t * EDIM + e];
        const float* bm = dbc + (long)t * DBCW + RNK;
        float dx = d * xv;
        #pragma unroll
        for (int n = 0; n < NS; ++n) {
            float a = __expf(d * Aa[n]);
            h[n] = fmaf(a, h[n], dx * bm[n]);
            Pp[n] *= a;
        }
    }
    #pragma unroll
    for (int n = 0; n < NS; ++n) {
        P [(long)(c * NS + n) * EDIM + e] = Pp[n];
        Hf[(long)(c * NS + n) * EDIM + e] = h[n];
    }
}

__global__ __launch_bounds__(128) void scan_phaseB(
    const float* __restrict__ P, float* __restrict__ Hf)
{
    int g = blockIdx.x * 128 + threadIdx.x;
    int e = g & (EDIM - 1);
    int n = g >> 11;
    float h = 0.f;
    for (int c = 0; c < NCH; ++c) {
        long idx = (long)(c * NS + n) * EDIM + e;
        float p = P[idx];
        float f = Hf[idx];
        Hf[idx] = h;
        h = fmaf(p, h, f);
    }
}

// Phase C: recompute local scan with prefix; u = (y + D*x) * silu(z) -> bf16
__global__ __launch_bounds__(256) void scan_phaseC(
    const float* __restrict__ delta, const float* __restrict__ xr,
    const float* __restrict__ dbc, const float* __restrict__ A_log,
    const float* __restrict__ Hf, const float* __restrict__ Dp,
    const float* __restrict__ z, ushort* __restrict__ ubf)
{
    int g = blockIdx.x * 256 + threadIdx.x;
    int e = g & (EDIM - 1);
    int c = g >> 11;
    float Aa[NS], h[NS];
    #pragma unroll
    for (int n = 0; n < NS; ++n) {
        Aa[n] = -__expf(A_log[e * NS + n]);
        h[n] = Hf[(long)(c * NS + n) * EDIM + e];
    }
    float dD = Dp[e];
    int t0 = c * LC;
    for (int t = t0; t < t0 + LC; ++t) {
        float d  = delta[(long)t * EDIM + e];
        float xv = xr[(long)t * EDIM + e];
        const float* bm = dbc + (long)t * DBCW + RNK;
        const float* cm = dbc + (long)t * DBCW + RNK + NS;
        float dx = d * xv;
        float y = 0.f;
        #pragma unroll
        for (int n = 0; n < NS; ++n) {
            float a = __expf(d * Aa[n]);
            h[n] = fmaf(a, h[n], dx * bm[n]);
            y = fmaf(h[n], cm[n], y);
        }
        y = fmaf(dD, xv, y);
        float zv = z[(long)t * EDIM + e];
        float sz = zv / (1.f + __expf(-zv));
        ubf[(long)t * EDIM + e] = f2bf(y * sz);
    }
}

// ---------------------------------------------------------------------------
extern "C" void kernel_launch(void* const* d_in, const int* in_sizes, int n_in,
                              void* d_out, int out_size, void* d_ws, size_t ws_size,
                              hipStream_t stream) {
    const float* x         = (const float*)d_in[0];
    const float* in_proj_w = (const float*)d_in[1];
    const float* conv_w    = (const float*)d_in[2];
    const float* conv_b    = (const float*)d_in[3];
    const float* x_proj_w  = (const float*)d_in[4];
    const float* dt_proj_w = (const float*)d_in[5];
    const float* dt_proj_b = (const float*)d_in[6];
    const float* A_log     = (const float*)d_in[7];
    const float* Dp        = (const float*)d_in[8];
    const float* out_proj_w= (const float*)d_in[9];
    float* out = (float*)d_out;

    float* ws = (float*)d_ws;
    const long M1 = 1048576;
    // Region A [0, 4M): xr_f32 -> Pbuf(3M) -> {P(2M) | ubf(2M..4M)}
    float*  xr_f32 = ws;
    float*  Pbuf   = ws;
    float*  P      = ws;
    ushort* ubf    = (ushort*)(ws + 2 * M1);
    // Region B [4M, 8M): z_f32
    float*  z_f32  = ws + 4 * M1;
    // Region C [8M, 12M): xrc
    float*  xrc    = ws + 8 * M1;
    // Region D [12M, 16M): {xbf(1M)+w1bf(2M)} -> delta(4M) -> Gp(4M)
    ushort* xbf    = (ushort*)(ws + 12 * M1);
    ushort* w1bf   = (ushort*)(ws + 13 * M1);
    float*  delta  = ws + 12 * M1;
    float*  Gp     = ws + 12 * M1;
    // Region E [16M, 18M): Hf
    float*  Hf     = ws + 16 * M1;
    // Region I [18M, 19M): w4bf
    ushort* w4bf   = (ushort*)(ws + 18 * M1);
    // Region J [19M, ...): dbc (196608)
    float*  dbc    = ws + 19 * M1;

    dim3 blk(256);

    // casts
    cast_all<<<8192, blk, 0, stream>>>(x, in_proj_w, out_proj_w, xbf, w1bf, w4bf);

    // G1: [xr|z] = x @ in_proj_w^T   [2048,4096] k=1024
    gemm_nt_bf16<<<(LSEQ / 128) * (4 * EDIM / 256), blk, 0, stream>>>(
        xbf, DM, w1bf, DM, xr_f32, z_f32, EDIM, EDIM, 0, DM, 2 * EDIM / 128,
        (LSEQ / 128) * (4 * EDIM / 256));

    // conv + silu -> xrc
    conv_silu<<<(LSEQ * EDIM) / 1024, blk, 0, stream>>>(xr_f32, conv_w, conv_b, xrc);

    // G2: dbc = xrc @ x_proj_w^T  [2048,96] k=2048, split-K x16
    gemm2_splitk<<<dim3(16, LSEQ / 32), blk, 0, stream>>>(xrc, x_proj_w, Pbuf);
    gemm2_reduce<<<(LSEQ * DBCW) / 256, blk, 0, stream>>>(Pbuf, dbc);

    // G3: delta = softplus(dbc[:, :64] @ dt_proj_w^T + b)  [2048,2048] k=64
    gemm_nt_f32<<<dim3(EDIM / BN, LSEQ / BM), blk, 0, stream>>>(
        dbc, DBCW, dt_proj_w, RNK, delta, EDIM, LSEQ, EDIM, RNK, dt_proj_b, 1);

    // scan
    scan_phaseA<<<(NCH * EDIM) / 256, blk, 0, stream>>>(delta, xrc, dbc, A_log, P, Hf);
    scan_phaseB<<<(EDIM * NS) / 128, dim3(128), 0, stream>>>(P, Hf);
    scan_phaseC<<<(NCH * EDIM) / 256, blk, 0, stream>>>(
        delta, xrc, dbc, A_log, Hf, Dp, z_f32, ubf);

    // G4: out = u @ out_proj_w^T  [2048,1024] k=2048, split-K x2
    gemm_nt_bf16<<<2 * (LSEQ / 128) * (DM / 128), blk, 0, stream>>>(
        ubf, EDIM, w4bf, EDIM, Gp, Gp, 1 << 30, DM, (long)LSEQ * DM, DM, DM / 128,
        (LSEQ / 128) * (DM / 128));
    g4_reduce<<<(LSEQ * DM) / 1024, blk, 0, stream>>>(Gp, out);
}

// Round 4
// 203.803 us; speedup vs baseline: 4.3698x; 1.0230x over previous
//
#include <hip/hip_runtime.h>
#include <math.h>

#define LSEQ 2048
#define DM   1024
#define EDIM 2048
#define RNK  64
#define NS   16
#define DBCW 96          // R + 2N
#define LC   32          // scan chunk length
#define NCH  (LSEQ / LC) // 64 chunks
#define NSEG 8           // chunks per segment (tree scan)
#define SPLITK2 16       // G2 split-K factor

typedef __attribute__((ext_vector_type(4))) float f32x4;
typedef __attribute__((ext_vector_type(8))) __bf16 bf16x8;

__device__ __forceinline__ ushort f2bf(float f) {
    unsigned u = __float_as_uint(f);
    unsigned r = (u + 0x7fffu + ((u >> 16) & 1u)) >> 16;
    return (ushort)r;
}
__device__ __forceinline__ float bf2f(ushort u) {
    return __uint_as_float(((unsigned)u) << 16);
}

// ---------------------------------------------------------------------------
// Fused prep: casts x/in_proj_w/out_proj_w/x_proj_w to bf16, zero-pads
// x_proj_w rows 96..127, zeroes d_out (for G4 atomics).
// Ranges in f32-element units, 4 per thread.
// ---------------------------------------------------------------------------
#define R0 2097152L               // x -> xbf
#define R1 (R0 + 4194304L)        // in_proj_w -> w1bf
#define R2 (R1 + 2097152L)        // out_proj_w -> w4bf
#define R3 (R2 + 196608L)         // x_proj_w -> xpw_pad rows 0..95
#define R4 (R3 + 2097152L)        // zero out
#define R5 (R4 + 32768L)          // zero xpw_pad tail (rows 96..127)

__global__ __launch_bounds__(256) void prep_all(
    const float* __restrict__ x, const float* __restrict__ w1,
    const float* __restrict__ w4, const float* __restrict__ xpw,
    ushort* __restrict__ xbf, ushort* __restrict__ w1bf,
    ushort* __restrict__ w4bf, ushort* __restrict__ xpw_pad,
    float* __restrict__ out)
{
    long idx4 = ((long)blockIdx.x * 256 + threadIdx.x) * 4;
    if (idx4 >= R5) return;
    if (idx4 >= R4) {   // zero xpw_pad tail: f32 view starting at us-index 196608
        long rel = idx4 - R4;
        float* p = (float*)(xpw_pad + 196608);
        *reinterpret_cast<float4*>(&p[rel]) = make_float4(0.f, 0.f, 0.f, 0.f);
        return;
    }
    if (idx4 >= R3) {   // zero out
        long rel = idx4 - R3;
        *reinterpret_cast<float4*>(&out[rel]) = make_float4(0.f, 0.f, 0.f, 0.f);
        return;
    }
    const float* src; ushort* dst; long rel;
    if (idx4 < R0)      { src = x;   dst = xbf;     rel = idx4; }
    else if (idx4 < R1) { src = w1;  dst = w1bf;    rel = idx4 - R0; }
    else if (idx4 < R2) { src = w4;  dst = w4bf;    rel = idx4 - R1; }
    else                { src = xpw; dst = xpw_pad; rel = idx4 - R2; }
    float4 v = *reinterpret_cast<const float4*>(&src[rel]);
    ushort4 o = make_ushort4(f2bf(v.x), f2bf(v.y), f2bf(v.z), f2bf(v.w));
    *reinterpret_cast<ushort4*>(&dst[rel]) = o;
}

// ---------------------------------------------------------------------------
// bf16 MFMA NT GEMM: C = A[M,K]*B[N,K]^T. 128x128 tile, BK=32, 4 waves,
// 16x16x32 MFMA. split-K via blocks_per_k; column-split dual output.
// emode: 0 = f32 store, 1 = bf16 store, 2 = f32 atomicAdd.
// ---------------------------------------------------------------------------
__global__ __launch_bounds__(256) void gemm_nt_bf16(
    const ushort* __restrict__ A, int lda,
    const ushort* __restrict__ B, int ldb,
    void* __restrict__ C0v, void* __restrict__ C1v, int csplit, int ldc,
    long cplane, int klen, int grid_n, int blocks_per_k, int emode)
{
    __shared__ ushort As[128 * 32];   // [row][32 bf16 = 64B rows], linear
    __shared__ ushort Bs[128 * 32];
    const int tid = threadIdx.x;
    const int wave = tid >> 6;
    const int lane = tid & 63;
    const int kch = blockIdx.x / blocks_per_k;
    const int rem = blockIdx.x % blocks_per_k;
    const int bm = (rem / grid_n) * 128;
    const int bn = (rem % grid_n) * 128;
    const int wm = (wave & 1) * 64;
    const int wn = (wave >> 1) * 64;
    const int koff = kch * klen;

    f32x4 acc[4][4] = {};

    const int offT = tid * 16;
    const char* Ab = (const char*)A;
    const char* Bb = (const char*)B;
    char* AsB = (char*)As;
    char* BsB = (char*)Bs;

    for (int k0 = 0; k0 < klen; k0 += 32) {
        __syncthreads();
        #pragma unroll
        for (int r = 0; r < 2; ++r) {
            int off = r * 4096 + offT;
            int row = off >> 6;
            int kb = off & 63;
            __builtin_amdgcn_global_load_lds(
                (const __attribute__((address_space(1))) void*)
                    (Ab + ((long)(bm + row) * lda + koff + k0) * 2 + kb),
                (__attribute__((address_space(3))) void*)
                    (AsB + r * 4096 + wave * 1024), 16, 0, 0);
            __builtin_amdgcn_global_load_lds(
                (const __attribute__((address_space(1))) void*)
                    (Bb + ((long)(bn + row) * ldb + koff + k0) * 2 + kb),
                (__attribute__((address_space(3))) void*)
                    (BsB + r * 4096 + wave * 1024), 16, 0, 0);
        }
        __syncthreads();

        bf16x8 af[4], bfr[4];
        #pragma unroll
        for (int i = 0; i < 4; ++i) {
            int ar = wm + i * 16 + (lane & 15);
            af[i]  = *reinterpret_cast<const bf16x8*>(AsB + ar * 64 + (lane >> 4) * 16);
            int br = wn + i * 16 + (lane & 15);
            bfr[i] = *reinterpret_cast<const bf16x8*>(BsB + br * 64 + (lane >> 4) * 16);
        }
        #pragma unroll
        for (int i = 0; i < 4; ++i)
            #pragma unroll
            for (int j = 0; j < 4; ++j)
                acc[i][j] = __builtin_amdgcn_mfma_f32_16x16x32_bf16(
                    af[i], bfr[j], acc[i][j], 0, 0, 0);
    }

    // C/D layout: col = lane&15, row = (lane>>4)*4 + q
    #pragma unroll
    for (int i = 0; i < 4; ++i) {
        int row0 = bm + wm + i * 16 + (lane >> 4) * 4;
        #pragma unroll
        for (int j = 0; j < 4; ++j) {
            int col = bn + wn + j * 16 + (lane & 15);
            int side = (col < csplit) ? 0 : 1;
            int cc = side ? (col - csplit) : col;
            #pragma unroll
            for (int q = 0; q < 4; ++q) {
                float v = acc[i][j][q];
                long oi = (long)(row0 + q) * ldc + cc;
                if (emode == 1) {
                    ushort* U = side ? (ushort*)C1v : (ushort*)C0v;
                    U[oi] = f2bf(v);
                } else if (emode == 2) {
                    float* F = side ? (float*)C1v : (float*)C0v;
                    atomicAdd(&F[oi], v);
                } else {
                    float* F = side ? (float*)C1v : (float*)C0v;
                    if (!side) F += (long)kch * cplane;
                    F[oi] = v;
                }
            }
        }
    }
}

// ---------------------------------------------------------------------------
// f32 NT GEMM (G3): C[M,N] = A[M,K]*B[N,K]^T (+softplus+bias epi)
// ---------------------------------------------------------------------------
#define BM 64
#define BN 64
#define BK 16

__global__ __launch_bounds__(256) void gemm_nt_f32(
    const float* __restrict__ A, int lda,
    const float* __restrict__ B, int ldb,
    float* __restrict__ C, int ldc,
    int M, int N, int K,
    const float* __restrict__ bias, int epi)
{
    __shared__ float As[BK][BM + 4];
    __shared__ float Bs[BK][BN + 4];
    const int bm = blockIdx.y * BM;
    const int bn = blockIdx.x * BN;
    const int tid = threadIdx.x;
    const int tx = tid & 15;
    const int ty = tid >> 4;
    const int kc = tid & 15;
    const int r0 = tid >> 4;

    float acc[4][4] = {};

    for (int k0 = 0; k0 < K; k0 += BK) {
        #pragma unroll
        for (int p = 0; p < 4; ++p) {
            int r = r0 + p * 16;
            As[kc][r] = A[(long)(bm + r) * lda + k0 + kc];
        }
        #pragma unroll
        for (int p = 0; p < 4; ++p) {
            int r = r0 + p * 16;
            Bs[kc][r] = B[(long)(bn + r) * ldb + k0 + kc];
        }
        __syncthreads();
        #pragma unroll
        for (int kk = 0; kk < BK; ++kk) {
            float4 a4 = *reinterpret_cast<const float4*>(&As[kk][ty * 4]);
            float4 b4 = *reinterpret_cast<const float4*>(&Bs[kk][tx * 4]);
            float av[4] = {a4.x, a4.y, a4.z, a4.w};
            float bv[4] = {b4.x, b4.y, b4.z, b4.w};
            #pragma unroll
            for (int i = 0; i < 4; ++i)
                #pragma unroll
                for (int j = 0; j < 4; ++j)
                    acc[i][j] = fmaf(av[i], bv[j], acc[i][j]);
        }
        __syncthreads();
    }

    #pragma unroll
    for (int i = 0; i < 4; ++i) {
        int r = bm + ty * 4 + i;
        #pragma unroll
        for (int j = 0; j < 4; ++j) {
            int c = bn + tx * 4 + j;
            float v = acc[i][j];
            if (epi == 1) {
                v += bias[c];
                v = fmaxf(v, 0.f) + log1pf(__expf(-fabsf(v)));
            }
            C[(long)r * ldc + c] = v;
        }
    }
}

// G2 reduce: dbc = sum over SPLITK2 partial planes
__global__ __launch_bounds__(256) void gemm2_reduce(
    const float* __restrict__ Pb, float* __restrict__ dbc)
{
    int idx = blockIdx.x * 256 + threadIdx.x;   // 2048*96
    float s = 0.f;
    #pragma unroll
    for (int c = 0; c < SPLITK2; ++c) s += Pb[(long)c * LSEQ * DBCW + idx];
    dbc[idx] = s;
}

// ---------------------------------------------------------------------------
// Depthwise causal conv (K=4) + bias + SiLU. bf16 in/out, f32 compute.
// 8 elems/thread.
// ---------------------------------------------------------------------------
__global__ __launch_bounds__(256) void conv_silu(
    const ushort* __restrict__ xr, const float* __restrict__ w,
    const float* __restrict__ b, ushort* __restrict__ xrc)
{
    int idx = blockIdx.x * 256 + threadIdx.x;   // l*256 + e8grp
    int l = idx >> 8;
    int e8 = (idx & 255) << 3;
    uint4 zero = make_uint4(0, 0, 0, 0);
    uint4 v0 = (l >= 3) ? *reinterpret_cast<const uint4*>(&xr[(long)(l - 3) * EDIM + e8]) : zero;
    uint4 v1 = (l >= 2) ? *reinterpret_cast<const uint4*>(&xr[(long)(l - 2) * EDIM + e8]) : zero;
    uint4 v2 = (l >= 1) ? *reinterpret_cast<const uint4*>(&xr[(long)(l - 1) * EDIM + e8]) : zero;
    uint4 v3 = *reinterpret_cast<const uint4*>(&xr[(long)l * EDIM + e8]);
    unsigned p0[4] = {v0.x, v0.y, v0.z, v0.w};
    unsigned p1[4] = {v1.x, v1.y, v1.z, v1.w};
    unsigned p2[4] = {v2.x, v2.y, v2.z, v2.w};
    unsigned p3[4] = {v3.x, v3.y, v3.z, v3.w};
    ushort o[8];
    #pragma unroll
    for (int h = 0; h < 4; ++h) {
        #pragma unroll
        for (int s = 0; s < 2; ++s) {
            int j = h * 2 + s;
            float r0 = bf2f((ushort)(s ? (p0[h] >> 16) : (p0[h] & 0xffff)));
            float r1 = bf2f((ushort)(s ? (p1[h] >> 16) : (p1[h] & 0xffff)));
            float r2 = bf2f((ushort)(s ? (p2[h] >> 16) : (p2[h] & 0xffff)));
            float r3 = bf2f((ushort)(s ? (p3[h] >> 16) : (p3[h] & 0xffff)));
            float4 wj = *reinterpret_cast<const float4*>(&w[(e8 + j) * 4]);
            float acc = b[e8 + j];
            acc = fmaf(wj.x, r0, acc);
            acc = fmaf(wj.y, r1, acc);
            acc = fmaf(wj.z, r2, acc);
            acc = fmaf(wj.w, r3, acc);
            o[j] = f2bf(acc / (1.f + __expf(-acc)));
        }
    }
    *reinterpret_cast<ushort4*>(&xrc[(long)l * EDIM + e8])     =
        make_ushort4(o[0], o[1], o[2], o[3]);
    *reinterpret_cast<ushort4*>(&xrc[(long)l * EDIM + e8 + 4]) =
        make_ushort4(o[4], o[5], o[6], o[7]);
}

// ---------------------------------------------------------------------------
// Selective scan. Phase A: local scan per (chunk, e), record decay product P
// and local final Hf. Layout [c][n][e].
// ---------------------------------------------------------------------------
__global__ __launch_bounds__(256) void scan_phaseA(
    const float* __restrict__ delta, const ushort* __restrict__ xr,
    const float* __restrict__ dbc, const float* __restrict__ A_log,
    float* __restrict__ P, float* __restrict__ Hf)
{
    int g = blockIdx.x * 256 + threadIdx.x;
    int e = g & (EDIM - 1);
    int c = g >> 11;
    float Aa[NS], h[NS], Pp[NS];
    #pragma unroll
    for (int n = 0; n < NS; ++n) {
        Aa[n] = -__expf(A_log[e * NS + n]);
        h[n] = 0.f;
        Pp[n] = 1.f;
    }
    int t0 = c * LC;
    for (int t = t0; t < t0 + LC; ++t) {
        float d  = delta[(long)t * EDIM + e];
        float xv = bf2f(xr[(long)t * EDIM + e]);
        const float* bm = dbc + (long)t * DBCW + RNK;
        float dx = d * xv;
        #pragma unroll
        for (int n = 0; n < NS; ++n) {
            float a = __expf(d * Aa[n]);
            h[n] = fmaf(a, h[n], dx * bm[n]);
            Pp[n] *= a;
        }
    }
    #pragma unroll
    for (int n = 0; n < NS; ++n) {
        P [(long)(c * NS + n) * EDIM + e] = Pp[n];
        Hf[(long)(c * NS + n) * EDIM + e] = h[n];
    }
}

// Phase B1: per (e,n,segment): within-segment prefix over 8 chunks.
// Overwrites P[c] with within-seg prefix decay product, Hf[c] with
// within-seg prefix h; writes segment summary (Sp, Sf).
__global__ __launch_bounds__(256) void scan_phaseB1(
    float* __restrict__ P, float* __restrict__ Hf,
    float* __restrict__ Sp, float* __restrict__ Sf)
{
    int gid = blockIdx.x * 256 + threadIdx.x;   // EDIM*NS*NSEG
    int e = gid & (EDIM - 1);
    int n = (gid >> 11) & (NS - 1);
    int g = gid >> 15;
    float h = 0.f, pp = 1.f;
    for (int c = g * NSEG; c < g * NSEG + NSEG; ++c) {
        long idx = (long)(c * NS + n) * EDIM + e;
        float p = P[idx];
        float f = Hf[idx];
        Hf[idx] = h;
        P[idx] = pp;
        h = fmaf(p, h, f);
        pp *= p;
    }
    long si = (long)(g * NS + n) * EDIM + e;
    Sp[si] = pp;
    Sf[si] = h;
}

// Phase B2: scan 8 segment summaries per (e,n); Sf[g] <- segment prefix h.
__global__ __launch_bounds__(256) void scan_phaseB2(
    const float* __restrict__ Sp, float* __restrict__ Sf)
{
    int gid = blockIdx.x * 256 + threadIdx.x;   // EDIM*NS
    int e = gid & (EDIM - 1);
    int n = gid >> 11;
    float h = 0.f;
    for (int g = 0; g < NSEG; ++g) {
        long idx = (long)(g * NS + n) * EDIM + e;
        float p = Sp[idx];
        float f = Sf[idx];
        Sf[idx] = h;
        h = fmaf(p, h, f);
    }
}

// Phase C: h_in(c) = P_within(c)*Sf(seg) + Hf_within(c); local scan with
// prefix; u = (y + D*x) * silu(z) -> bf16
__global__ __launch_bounds__(256) void scan_phaseC(
    const float* __restrict__ delta, const ushort* __restrict__ xr,
    const float* __restrict__ dbc, const float* __restrict__ A_log,
    const float* __restrict__ P, const float* __restrict__ Hf,
    const float* __restrict__ Sf, const float* __restrict__ Dp,
    const ushort* __restrict__ z, ushort* __restrict__ ubf)
{
    int gid = blockIdx.x * 256 + threadIdx.x;
    int e = gid & (EDIM - 1);
    int c = gid >> 11;
    int g = c >> 3;
    float Aa[NS], h[NS];
    #pragma unroll
    for (int n = 0; n < NS; ++n) {
        Aa[n] = -__expf(A_log[e * NS + n]);
        long ci = (long)(c * NS + n) * EDIM + e;
        long si = (long)(g * NS + n) * EDIM + e;
        h[n] = fmaf(P[ci], Sf[si], Hf[ci]);
    }
    float dD = Dp[e];
    int t0 = c * LC;
    for (int t = t0; t < t0 + LC; ++t) {
        float d  = delta[(long)t * EDIM + e];
        float xv = bf2f(xr[(long)t * EDIM + e]);
        const float* bm = dbc + (long)t * DBCW + RNK;
        const float* cm = dbc + (long)t * DBCW + RNK + NS;
        float dx = d * xv;
        float y = 0.f;
        #pragma unroll
        for (int n = 0; n < NS; ++n) {
            float a = __expf(d * Aa[n]);
            h[n] = fmaf(a, h[n], dx * bm[n]);
            y = fmaf(h[n], cm[n], y);
        }
        y = fmaf(dD, xv, y);
        float zv = bf2f(z[(long)t * EDIM + e]);
        float sz = zv / (1.f + __expf(-zv));
        ubf[(long)t * EDIM + e] = f2bf(y * sz);
    }
}

// ---------------------------------------------------------------------------
extern "C" void kernel_launch(void* const* d_in, const int* in_sizes, int n_in,
                              void* d_out, int out_size, void* d_ws, size_t ws_size,
                              hipStream_t stream) {
    const float* x         = (const float*)d_in[0];
    const float* in_proj_w = (const float*)d_in[1];
    const float* conv_w    = (const float*)d_in[2];
    const float* conv_b    = (const float*)d_in[3];
    const float* x_proj_w  = (const float*)d_in[4];
    const float* dt_proj_w = (const float*)d_in[5];
    const float* dt_proj_b = (const float*)d_in[6];
    const float* A_log     = (const float*)d_in[7];
    const float* Dp        = (const float*)d_in[8];
    const float* out_proj_w= (const float*)d_in[9];
    float* out = (float*)d_out;

    float* ws = (float*)d_ws;
    const long M1 = 1048576;
    // [0,3M): xbf(1M) + w1bf(2M), reused as Pb (3M) after G1
    ushort* xbf     = (ushort*)ws;
    ushort* w1bf    = (ushort*)(ws + 1 * M1);
    float*  Pb      = ws;
    // [3M, 3.25M): junk C1 for G2 cols 96..127
    float*  junk    = ws + 3 * M1;
    // [3.25M, 3.375M): xpw_pad (128x2048 bf16)
    ushort* xpw_pad = (ushort*)(ws + 3 * M1 + M1 / 4);
    // [3.5M, 4.5M): w4bf
    ushort* w4bf    = (ushort*)(ws + 3 * M1 + M1 / 2);
    // [4.5M, 6.5M): xrbf [2048][2048] bf16; reused as ubf after conv/scan
    ushort* xrbf    = (ushort*)(ws + 4 * M1 + M1 / 2);
    ushort* ubf     = xrbf;
    // [6.5M, 8.5M): zbf
    ushort* zbf     = (ushort*)(ws + 6 * M1 + M1 / 2);
    // [8.5M, 10.5M): xrcbf
    ushort* xrcbf   = (ushort*)(ws + 8 * M1 + M1 / 2);
    // [10.5M, 14.5M): delta f32
    float*  delta   = ws + 10 * M1 + M1 / 2;
    // [14.5M, 16.5M): P ; [16.5M, 18.5M): Hf
    float*  P       = ws + 14 * M1 + M1 / 2;
    float*  Hf      = ws + 16 * M1 + M1 / 2;
    // [18.5M, 18.75M): Sp ; [18.75M, 19M): Sf
    float*  Sp      = ws + 18 * M1 + M1 / 2;
    float*  Sf      = ws + 18 * M1 + 3 * M1 / 4;
    // [19M, ...): dbc
    float*  dbc     = ws + 19 * M1;

    dim3 blk(256);

    // prep: casts + zero-out + zero-pad
    prep_all<<<(R5 / 4 + 255) / 256, blk, 0, stream>>>(
        x, in_proj_w, out_proj_w, x_proj_w, xbf, w1bf, w4bf, xpw_pad, out);

    // G1: [xr|z](bf16) = x @ in_proj_w^T   [2048,4096] k=1024
    gemm_nt_bf16<<<512, blk, 0, stream>>>(
        xbf, DM, w1bf, DM, xrbf, zbf, EDIM, EDIM, 0, DM, 32, 512, 1);

    // conv + silu: xrbf -> xrcbf
    conv_silu<<<(LSEQ * EDIM) / 2048, blk, 0, stream>>>(xrbf, conv_w, conv_b, xrcbf);

    // G2: Pb[kch] = xrcbf[:, kch*128:+128] @ xpw_pad^T  (MFMA, split-K x16)
    gemm_nt_bf16<<<SPLITK2 * 16, blk, 0, stream>>>(
        xrcbf, EDIM, xpw_pad, EDIM, Pb, junk, DBCW, DBCW,
        (long)LSEQ * DBCW, EDIM / SPLITK2, 1, 16, 0);
    gemm2_reduce<<<(LSEQ * DBCW) / 256, blk, 0, stream>>>(Pb, dbc);

    // G3: delta = softplus(dbc[:, :64] @ dt_proj_w^T + b)  [2048,2048] k=64
    gemm_nt_f32<<<dim3(EDIM / BN, LSEQ / BM), blk, 0, stream>>>(
        dbc, DBCW, dt_proj_w, RNK, delta, EDIM, LSEQ, EDIM, RNK, dt_proj_b, 1);

    // scan
    scan_phaseA<<<(NCH * EDIM) / 256, blk, 0, stream>>>(
        delta, xrcbf, dbc, A_log, P, Hf);
    scan_phaseB1<<<(EDIM * NS * NSEG) / 256, blk, 0, stream>>>(P, Hf, Sp, Sf);
    scan_phaseB2<<<(EDIM * NS) / 256, blk, 0, stream>>>(Sp, Sf);
    scan_phaseC<<<(NCH * EDIM) / 256, blk, 0, stream>>>(
        delta, xrcbf, dbc, A_log, P, Hf, Sf, Dp, zbf, ubf);

    // G4: out += u @ out_proj_w^T  [2048,1024] k=2048, split-K x2, atomic
    gemm_nt_bf16<<<2 * 128, blk, 0, stream>>>(
        ubf, EDIM, w4bf, EDIM, out, out, 1 << 30, DM, 0, DM, 8, 128, 2);
}

// Round 5
// 192.165 us; speedup vs baseline: 4.6345x; 1.0606x over previous
//
#include <hip/hip_runtime.h>
#include <math.h>

#define LSEQ 2048
#define DM   1024
#define EDIM 2048
#define RNK  64
#define NS   16
#define DBCW 96          // R + 2N
#define LC   32          // scan chunk length
#define NCH  (LSEQ / LC) // 64 chunks
#define NSEG 8           // chunks per segment (tree scan)
#define SPLITK2 16       // G2 split-K factor

typedef __attribute__((ext_vector_type(4))) float f32x4;
typedef __attribute__((ext_vector_type(8))) __bf16 bf16x8;

__device__ __forceinline__ ushort f2bf(float f) {
    unsigned u = __float_as_uint(f);
    unsigned r = (u + 0x7fffu + ((u >> 16) & 1u)) >> 16;
    return (ushort)r;
}
__device__ __forceinline__ float bf2f(ushort u) {
    return __uint_as_float(((unsigned)u) << 16);
}

// ---------------------------------------------------------------------------
// Fused prep: casts x/in_proj_w/out_proj_w/x_proj_w to bf16, zero-pads
// x_proj_w rows 96..127. Ranges in f32-element units, 4 per thread.
// ---------------------------------------------------------------------------
#define R0 2097152L               // x -> xbf
#define R1 (R0 + 4194304L)        // in_proj_w -> w1bf
#define R2 (R1 + 2097152L)        // out_proj_w -> w4bf
#define R3 (R2 + 196608L)         // x_proj_w -> xpw_pad rows 0..95
#define R4 (R3 + 32768L)          // zero xpw_pad tail (rows 96..127)

__global__ __launch_bounds__(256) void prep_all(
    const float* __restrict__ x, const float* __restrict__ w1,
    const float* __restrict__ w4, const float* __restrict__ xpw,
    ushort* __restrict__ xbf, ushort* __restrict__ w1bf,
    ushort* __restrict__ w4bf, ushort* __restrict__ xpw_pad)
{
    long idx4 = ((long)blockIdx.x * 256 + threadIdx.x) * 4;
    if (idx4 >= R4) return;
    if (idx4 >= R3) {   // zero xpw_pad tail: f32 view starting at ushort 196608
        long rel = idx4 - R3;
        float* p = (float*)(xpw_pad + 196608);
        *reinterpret_cast<float4*>(&p[rel]) = make_float4(0.f, 0.f, 0.f, 0.f);
        return;
    }
    const float* src; ushort* dst; long rel;
    if (idx4 < R0)      { src = x;   dst = xbf;     rel = idx4; }
    else if (idx4 < R1) { src = w1;  dst = w1bf;    rel = idx4 - R0; }
    else if (idx4 < R2) { src = w4;  dst = w4bf;    rel = idx4 - R1; }
    else                { src = xpw; dst = xpw_pad; rel = idx4 - R2; }
    float4 v = *reinterpret_cast<const float4*>(&src[rel]);
    ushort4 o = make_ushort4(f2bf(v.x), f2bf(v.y), f2bf(v.z), f2bf(v.w));
    *reinterpret_cast<ushort4*>(&dst[rel]) = o;
}

// ---------------------------------------------------------------------------
// bf16 MFMA NT GEMM: C = A[M,K]*B[N,K]^T, f32 out. 128x128 tile, BK=32,
// 4 waves (2x2 of 64x64), 16x16x32 MFMA. split-K via blocks_per_k (C0 gets
// per-kch plane offset); column-split dual output (C0 col<csplit, C1 else).
// ---------------------------------------------------------------------------
__global__ __launch_bounds__(256) void gemm_nt_bf16(
    const ushort* __restrict__ A, int lda,
    const ushort* __restrict__ B, int ldb,
    float* __restrict__ C0, float* __restrict__ C1, int csplit, int ldc,
    long cplane, int klen, int grid_n, int blocks_per_k)
{
    __shared__ ushort As[128 * 32];   // [row][32 bf16 = 64B rows], linear
    __shared__ ushort Bs[128 * 32];
    const int tid = threadIdx.x;
    const int wave = tid >> 6;
    const int lane = tid & 63;
    const int kch = blockIdx.x / blocks_per_k;
    const int rem = blockIdx.x % blocks_per_k;
    const int bm = (rem / grid_n) * 128;
    const int bn = (rem % grid_n) * 128;
    const int wm = (wave & 1) * 64;
    const int wn = (wave >> 1) * 64;
    const int koff = kch * klen;
    C0 += (long)kch * cplane;

    f32x4 acc[4][4] = {};

    const int offT = tid * 16;
    const char* Ab = (const char*)A;
    const char* Bb = (const char*)B;
    char* AsB = (char*)As;
    char* BsB = (char*)Bs;

    for (int k0 = 0; k0 < klen; k0 += 32) {
        __syncthreads();
        #pragma unroll
        for (int r = 0; r < 2; ++r) {
            int off = r * 4096 + offT;
            int row = off >> 6;
            int kb = off & 63;
            __builtin_amdgcn_global_load_lds(
                (const __attribute__((address_space(1))) void*)
                    (Ab + ((long)(bm + row) * lda + koff + k0) * 2 + kb),
                (__attribute__((address_space(3))) void*)
                    (AsB + r * 4096 + wave * 1024), 16, 0, 0);
            __builtin_amdgcn_global_load_lds(
                (const __attribute__((address_space(1))) void*)
                    (Bb + ((long)(bn + row) * ldb + koff + k0) * 2 + kb),
                (__attribute__((address_space(3))) void*)
                    (BsB + r * 4096 + wave * 1024), 16, 0, 0);
        }
        __syncthreads();

        bf16x8 af[4], bfr[4];
        #pragma unroll
        for (int i = 0; i < 4; ++i) {
            int ar = wm + i * 16 + (lane & 15);
            af[i]  = *reinterpret_cast<const bf16x8*>(AsB + ar * 64 + (lane >> 4) * 16);
            int br = wn + i * 16 + (lane & 15);
            bfr[i] = *reinterpret_cast<const bf16x8*>(BsB + br * 64 + (lane >> 4) * 16);
        }
        #pragma unroll
        for (int i = 0; i < 4; ++i)
            #pragma unroll
            for (int j = 0; j < 4; ++j)
                acc[i][j] = __builtin_amdgcn_mfma_f32_16x16x32_bf16(
                    af[i], bfr[j], acc[i][j], 0, 0, 0);
    }

    // C/D layout: col = lane&15, row = (lane>>4)*4 + q
    #pragma unroll
    for (int i = 0; i < 4; ++i) {
        int row0 = bm + wm + i * 16 + (lane >> 4) * 4;
        #pragma unroll
        for (int j = 0; j < 4; ++j) {
            int col = bn + wn + j * 16 + (lane & 15);
            float* Cp;
            int cc;
            if (col < csplit) { Cp = C0; cc = col; }
            else              { Cp = C1; cc = col - csplit; }
            #pragma unroll
            for (int q = 0; q < 4; ++q)
                Cp[(long)(row0 + q) * ldc + cc] = acc[i][j][q];
        }
    }
}

// G4 reduce: out = Gp[0] + Gp[1], float4
__global__ __launch_bounds__(256) void g4_reduce(
    const float* __restrict__ Gp, float* __restrict__ out)
{
    long i4 = ((long)blockIdx.x * 256 + threadIdx.x) * 4;
    float4 a = *reinterpret_cast<const float4*>(&Gp[i4]);
    float4 b = *reinterpret_cast<const float4*>(&Gp[2097152 + i4]);
    float4 o = make_float4(a.x + b.x, a.y + b.y, a.z + b.z, a.w + b.w);
    *reinterpret_cast<float4*>(&out[i4]) = o;
}

// ---------------------------------------------------------------------------
// f32 NT GEMM (G3): C[M,N] = A[M,K]*B[N,K]^T (+softplus+bias epi)
// ---------------------------------------------------------------------------
#define BM 64
#define BN 64
#define BK 16

__global__ __launch_bounds__(256) void gemm_nt_f32(
    const float* __restrict__ A, int lda,
    const float* __restrict__ B, int ldb,
    float* __restrict__ C, int ldc,
    int M, int N, int K,
    const float* __restrict__ bias, int epi)
{
    __shared__ float As[BK][BM + 4];
    __shared__ float Bs[BK][BN + 4];
    const int bm = blockIdx.y * BM;
    const int bn = blockIdx.x * BN;
    const int tid = threadIdx.x;
    const int tx = tid & 15;
    const int ty = tid >> 4;
    const int kc = tid & 15;
    const int r0 = tid >> 4;

    float acc[4][4] = {};

    for (int k0 = 0; k0 < K; k0 += BK) {
        #pragma unroll
        for (int p = 0; p < 4; ++p) {
            int r = r0 + p * 16;
            As[kc][r] = A[(long)(bm + r) * lda + k0 + kc];
        }
        #pragma unroll
        for (int p = 0; p < 4; ++p) {
            int r = r0 + p * 16;
            Bs[kc][r] = B[(long)(bn + r) * ldb + k0 + kc];
        }
        __syncthreads();
        #pragma unroll
        for (int kk = 0; kk < BK; ++kk) {
            float4 a4 = *reinterpret_cast<const float4*>(&As[kk][ty * 4]);
            float4 b4 = *reinterpret_cast<const float4*>(&Bs[kk][tx * 4]);
            float av[4] = {a4.x, a4.y, a4.z, a4.w};
            float bv[4] = {b4.x, b4.y, b4.z, b4.w};
            #pragma unroll
            for (int i = 0; i < 4; ++i)
                #pragma unroll
                for (int j = 0; j < 4; ++j)
                    acc[i][j] = fmaf(av[i], bv[j], acc[i][j]);
        }
        __syncthreads();
    }

    #pragma unroll
    for (int i = 0; i < 4; ++i) {
        int r = bm + ty * 4 + i;
        #pragma unroll
        for (int j = 0; j < 4; ++j) {
            int c = bn + tx * 4 + j;
            float v = acc[i][j];
            if (epi == 1) {
                v += bias[c];
                v = fmaxf(v, 0.f) + log1pf(__expf(-fabsf(v)));
            }
            C[(long)r * ldc + c] = v;
        }
    }
}

// G2 reduce: dbc = sum over SPLITK2 partial planes
__global__ __launch_bounds__(256) void gemm2_reduce(
    const float* __restrict__ Pb, float* __restrict__ dbc)
{
    int idx = blockIdx.x * 256 + threadIdx.x;   // 2048*96
    float s = 0.f;
    #pragma unroll
    for (int c = 0; c < SPLITK2; ++c) s += Pb[(long)c * LSEQ * DBCW + idx];
    dbc[idx] = s;
}

// ---------------------------------------------------------------------------
// Depthwise causal conv (K=4) + bias + SiLU. f32 in, bf16 out, 4 elems/thread.
// ---------------------------------------------------------------------------
__global__ __launch_bounds__(256) void conv_silu(
    const float* __restrict__ xr, const float* __restrict__ w,
    const float* __restrict__ b, ushort* __restrict__ xrc)
{
    int idx = blockIdx.x * 256 + threadIdx.x;   // l*512 + e4
    int l = idx >> 9;
    int e4 = (idx & 511) << 2;
    float4 zero = make_float4(0.f, 0.f, 0.f, 0.f);
    float4 r0 = (l >= 3) ? *reinterpret_cast<const float4*>(&xr[(long)(l - 3) * EDIM + e4]) : zero;
    float4 r1 = (l >= 2) ? *reinterpret_cast<const float4*>(&xr[(long)(l - 2) * EDIM + e4]) : zero;
    float4 r2 = (l >= 1) ? *reinterpret_cast<const float4*>(&xr[(long)(l - 1) * EDIM + e4]) : zero;
    float4 r3 = *reinterpret_cast<const float4*>(&xr[(long)l * EDIM + e4]);
    float4 bb = *reinterpret_cast<const float4*>(&b[e4]);
    float rr0[4] = {r0.x, r0.y, r0.z, r0.w};
    float rr1[4] = {r1.x, r1.y, r1.z, r1.w};
    float rr2[4] = {r2.x, r2.y, r2.z, r2.w};
    float rr3[4] = {r3.x, r3.y, r3.z, r3.w};
    float bbv[4] = {bb.x, bb.y, bb.z, bb.w};
    ushort o[4];
    #pragma unroll
    for (int j = 0; j < 4; ++j) {
        float4 wj = *reinterpret_cast<const float4*>(&w[(e4 + j) * 4]);
        float acc = bbv[j];
        acc = fmaf(wj.x, rr0[j], acc);
        acc = fmaf(wj.y, rr1[j], acc);
        acc = fmaf(wj.z, rr2[j], acc);
        acc = fmaf(wj.w, rr3[j], acc);
        o[j] = f2bf(acc / (1.f + __expf(-acc)));
    }
    *reinterpret_cast<ushort4*>(&xrc[(long)l * EDIM + e4]) =
        make_ushort4(o[0], o[1], o[2], o[3]);
}

// ---------------------------------------------------------------------------
// Selective scan. Phase A: local scan per (chunk, e), record decay product P
// and local final Hf. Layout [c][n][e].
// ---------------------------------------------------------------------------
__global__ __launch_bounds__(256) void scan_phaseA(
    const float* __restrict__ delta, const ushort* __restrict__ xr,
    const float* __restrict__ dbc, const float* __restrict__ A_log,
    float* __restrict__ P, float* __restrict__ Hf)
{
    int g = blockIdx.x * 256 + threadIdx.x;
    int e = g & (EDIM - 1);
    int c = g >> 11;
    float Aa[NS], h[NS], Pp[NS];
    #pragma unroll
    for (int n = 0; n < NS; ++n) {
        Aa[n] = -__expf(A_log[e * NS + n]);
        h[n] = 0.f;
        Pp[n] = 1.f;
    }
    int t0 = c * LC;
    for (int t = t0; t < t0 + LC; ++t) {
        float d  = delta[(long)t * EDIM + e];
        float xv = bf2f(xr[(long)t * EDIM + e]);
        const float* bm = dbc + (long)t * DBCW + RNK;
        float dx = d * xv;
        #pragma unroll
        for (int n = 0; n < NS; ++n) {
            float a = __expf(d * Aa[n]);
            h[n] = fmaf(a, h[n], dx * bm[n]);
            Pp[n] *= a;
        }
    }
    #pragma unroll
    for (int n = 0; n < NS; ++n) {
        P [(long)(c * NS + n) * EDIM + e] = Pp[n];
        Hf[(long)(c * NS + n) * EDIM + e] = h[n];
    }
}

// Phase B1: per (e,n,segment): within-segment prefix over 8 chunks.
__global__ __launch_bounds__(256) void scan_phaseB1(
    float* __restrict__ P, float* __restrict__ Hf,
    float* __restrict__ Sp, float* __restrict__ Sf)
{
    int gid = blockIdx.x * 256 + threadIdx.x;   // EDIM*NS*NSEG
    int e = gid & (EDIM - 1);
    int n = (gid >> 11) & (NS - 1);
    int g = gid >> 15;
    float h = 0.f, pp = 1.f;
    for (int c = g * NSEG; c < g * NSEG + NSEG; ++c) {
        long idx = (long)(c * NS + n) * EDIM + e;
        float p = P[idx];
        float f = Hf[idx];
        Hf[idx] = h;
        P[idx] = pp;
        h = fmaf(p, h, f);
        pp *= p;
    }
    long si = (long)(g * NS + n) * EDIM + e;
    Sp[si] = pp;
    Sf[si] = h;
}

// Phase B2: scan 8 segment summaries per (e,n); Sf[g] <- segment prefix h.
__global__ __launch_bounds__(256) void scan_phaseB2(
    const float* __restrict__ Sp, float* __restrict__ Sf)
{
    int gid = blockIdx.x * 256 + threadIdx.x;   // EDIM*NS
    int e = gid & (EDIM - 1);
    int n = gid >> 11;
    float h = 0.f;
    for (int g = 0; g < NSEG; ++g) {
        long idx = (long)(g * NS + n) * EDIM + e;
        float p = Sp[idx];
        float f = Sf[idx];
        Sf[idx] = h;
        h = fmaf(p, h, f);
    }
}

// Phase C: h_in(c) = P_within(c)*Sf(seg) + Hf_within(c); local scan with
// prefix; u = (y + D*x) * silu(z) -> bf16
__global__ __launch_bounds__(256) void scan_phaseC(
    const float* __restrict__ delta, const ushort* __restrict__ xr,
    const float* __restrict__ dbc, const float* __restrict__ A_log,
    const float* __restrict__ P, const float* __restrict__ Hf,
    const float* __restrict__ Sf, const float* __restrict__ Dp,
    const float* __restrict__ z, ushort* __restrict__ ubf)
{
    int gid = blockIdx.x * 256 + threadIdx.x;
    int e = gid & (EDIM - 1);
    int c = gid >> 11;
    int g = c >> 3;
    float Aa[NS], h[NS];
    #pragma unroll
    for (int n = 0; n < NS; ++n) {
        Aa[n] = -__expf(A_log[e * NS + n]);
        long ci = (long)(c * NS + n) * EDIM + e;
        long si = (long)(g * NS + n) * EDIM + e;
        h[n] = fmaf(P[ci], Sf[si], Hf[ci]);
    }
    float dD = Dp[e];
    int t0 = c * LC;
    for (int t = t0; t < t0 + LC; ++t) {
        float d  = delta[(long)t * EDIM + e];
        float xv = bf2f(xr[(long)t * EDIM + e]);
        const float* bm = dbc + (long)t * DBCW + RNK;
        const float* cm = dbc + (long)t * DBCW + RNK + NS;
        float dx = d * xv;
        float y = 0.f;
        #pragma unroll
        for (int n = 0; n < NS; ++n) {
            float a = __expf(d * Aa[n]);
            h[n] = fmaf(a, h[n], dx * bm[n]);
            y = fmaf(h[n], cm[n], y);
        }
        y = fmaf(dD, xv, y);
        float zv = z[(long)t * EDIM + e];
        float sz = zv / (1.f + __expf(-zv));
        ubf[(long)t * EDIM + e] = f2bf(y * sz);
    }
}

// ---------------------------------------------------------------------------
extern "C" void kernel_launch(void* const* d_in, const int* in_sizes, int n_in,
                              void* d_out, int out_size, void* d_ws, size_t ws_size,
                              hipStream_t stream) {
    const float* x         = (const float*)d_in[0];
    const float* in_proj_w = (const float*)d_in[1];
    const float* conv_w    = (const float*)d_in[2];
    const float* conv_b    = (const float*)d_in[3];
    const float* x_proj_w  = (const float*)d_in[4];
    const float* dt_proj_w = (const float*)d_in[5];
    const float* dt_proj_b = (const float*)d_in[6];
    const float* A_log     = (const float*)d_in[7];
    const float* Dp        = (const float*)d_in[8];
    const float* out_proj_w= (const float*)d_in[9];
    float* out = (float*)d_out;

    float* ws = (float*)d_ws;
    const long M1 = 1048576;
    // [0,1M): xbf ; [1M,3M): w1bf  -> after G1 dead; Pb = [0,3M);
    //   after gemm2_reduce Pb dead; ubf = [0,2M) (4M ushort)
    ushort* xbf     = (ushort*)ws;
    ushort* w1bf    = (ushort*)(ws + 1 * M1);
    float*  Pb      = ws;
    ushort* ubf     = (ushort*)ws;
    // [3M, 3.0625M): junk C1 for G2 cols 96..127
    float*  junk    = ws + 3 * M1;
    // [3.25M, 3.375M): xpw_pad (128x2048 bf16)
    ushort* xpw_pad = (ushort*)(ws + 3 * M1 + M1 / 4);
    // [3.5M, 4.5M): w4bf
    ushort* w4bf    = (ushort*)(ws + 3 * M1 + M1 / 2);
    // [4.5M, 8.5M): xr_f32; dead after conv -> delta overlays
    float*  xr_f32  = ws + 4 * M1 + M1 / 2;
    float*  delta   = xr_f32;
    // [8.5M, 12.5M): z_f32; dead after scanC -> Gp overlays
    float*  z_f32   = ws + 8 * M1 + M1 / 2;
    float*  Gp      = z_f32;
    // [12.5M, 14.5M): xrcbf (4M ushort)
    ushort* xrcbf   = (ushort*)(ws + 12 * M1 + M1 / 2);
    // [14.5M, 16.5M): P ; [16.5M, 18.5M): Hf
    float*  P       = ws + 14 * M1 + M1 / 2;
    float*  Hf      = ws + 16 * M1 + M1 / 2;
    // [18.5M, 18.75M): Sp ; [18.75M, 19M): Sf
    float*  Sp      = ws + 18 * M1 + M1 / 2;
    float*  Sf      = ws + 18 * M1 + 3 * M1 / 4;
    // [19M, ...): dbc
    float*  dbc     = ws + 19 * M1;

    dim3 blk(256);

    // prep: casts + x_proj_w pad
    prep_all<<<(R4 / 4 + 255) / 256, blk, 0, stream>>>(
        x, in_proj_w, out_proj_w, x_proj_w, xbf, w1bf, w4bf, xpw_pad);

    // G1: [xr|z](f32 planes) = x @ in_proj_w^T   [2048,4096] k=1024
    gemm_nt_bf16<<<512, blk, 0, stream>>>(
        xbf, DM, w1bf, DM, xr_f32, z_f32, EDIM, EDIM, 0, DM, 32, 512);

    // conv + silu: xr_f32 -> xrcbf (bf16)
    conv_silu<<<(LSEQ * EDIM) / 1024, blk, 0, stream>>>(xr_f32, conv_w, conv_b, xrcbf);

    // G2: Pb[kch] = xrcbf[:, kch*128:+128] @ xpw_pad^T  (MFMA, split-K x16)
    gemm_nt_bf16<<<SPLITK2 * 16, blk, 0, stream>>>(
        xrcbf, EDIM, xpw_pad, EDIM, Pb, junk, DBCW, DBCW,
        (long)LSEQ * DBCW, EDIM / SPLITK2, 1, 16);
    gemm2_reduce<<<(LSEQ * DBCW) / 256, blk, 0, stream>>>(Pb, dbc);

    // G3: delta = softplus(dbc[:, :64] @ dt_proj_w^T + b)  [2048,2048] k=64
    gemm_nt_f32<<<dim3(EDIM / BN, LSEQ / BM), blk, 0, stream>>>(
        dbc, DBCW, dt_proj_w, RNK, delta, EDIM, LSEQ, EDIM, RNK, dt_proj_b, 1);

    // scan
    scan_phaseA<<<(NCH * EDIM) / 256, blk, 0, stream>>>(
        delta, xrcbf, dbc, A_log, P, Hf);
    scan_phaseB1<<<(EDIM * NS * NSEG) / 256, blk, 0, stream>>>(P, Hf, Sp, Sf);
    scan_phaseB2<<<(EDIM * NS) / 256, blk, 0, stream>>>(Sp, Sf);
    scan_phaseC<<<(NCH * EDIM) / 256, blk, 0, stream>>>(
        delta, xrcbf, dbc, A_log, P, Hf, Sf, Dp, z_f32, ubf);

    // G4: Gp[kch] = u @ out_proj_w^T  [2048,1024] k=2048, split-K x2
    gemm_nt_bf16<<<2 * 128, blk, 0, stream>>>(
        ubf, EDIM, w4bf, EDIM, Gp, junk, 1 << 30, DM,
        (long)LSEQ * DM, EDIM / 2, 8, 128);
    g4_reduce<<<(LSEQ * DM) / 1024, blk, 0, stream>>>(Gp, out);
}

// Round 7
// 182.508 us; speedup vs baseline: 4.8797x; 1.0529x over previous
//
#include <hip/hip_runtime.h>
#include <math.h>

#define LSEQ 2048
#define DM   1024
#define EDIM 2048
#define RNK  64
#define NS   16
#define DBCW 96          // R + 2N
#define LC   32          // scan chunk length
#define NCH  (LSEQ / LC) // 64 chunks
#define NSEG 8           // chunks per segment (tree scan)
#define SPLITK2 16       // G2 split-K factor
#define SPLITK4 4        // G4 split-K factor

typedef __attribute__((ext_vector_type(4))) float f32x4;
typedef __attribute__((ext_vector_type(8))) __bf16 bf16x8;

__device__ __forceinline__ ushort f2bf(float f) {
    unsigned u = __float_as_uint(f);
    unsigned r = (u + 0x7fffu + ((u >> 16) & 1u)) >> 16;
    return (ushort)r;
}
__device__ __forceinline__ float bf2f(ushort u) {
    return __uint_as_float(((unsigned)u) << 16);
}

// ---------------------------------------------------------------------------
// Fused prep: casts x/in_proj_w/out_proj_w/x_proj_w/dt_proj_w to bf16,
// zero-pads x_proj_w rows 96..127. Ranges in f32-element units, 4/thread.
// ---------------------------------------------------------------------------
#define R0 2097152L               // x -> xbf
#define R1 (R0 + 4194304L)        // in_proj_w -> w1bf
#define R2 (R1 + 2097152L)        // out_proj_w -> w4bf
#define R3 (R2 + 196608L)         // x_proj_w -> xpw_pad rows 0..95
#define R4 (R3 + 131072L)         // dt_proj_w -> w3bf
#define R5 (R4 + 32768L)          // zero xpw_pad tail (rows 96..127)

__global__ __launch_bounds__(256) void prep_all(
    const float* __restrict__ x, const float* __restrict__ w1,
    const float* __restrict__ w4, const float* __restrict__ xpw,
    const float* __restrict__ w3,
    ushort* __restrict__ xbf, ushort* __restrict__ w1bf,
    ushort* __restrict__ w4bf, ushort* __restrict__ xpw_pad,
    ushort* __restrict__ w3bf)
{
    long idx4 = ((long)blockIdx.x * 256 + threadIdx.x) * 4;
    if (idx4 >= R5) return;
    if (idx4 >= R4) {   // zero xpw_pad tail: f32 view starting at ushort 196608
        long rel = idx4 - R4;
        float* p = (float*)(xpw_pad + 196608);
        *reinterpret_cast<float4*>(&p[rel]) = make_float4(0.f, 0.f, 0.f, 0.f);
        return;
    }
    const float* src; ushort* dst; long rel;
    if (idx4 < R0)      { src = x;   dst = xbf;     rel = idx4; }
    else if (idx4 < R1) { src = w1;  dst = w1bf;    rel = idx4 - R0; }
    else if (idx4 < R2) { src = w4;  dst = w4bf;    rel = idx4 - R1; }
    else if (idx4 < R3) { src = xpw; dst = xpw_pad; rel = idx4 - R2; }
    else                { src = w3;  dst = w3bf;    rel = idx4 - R3; }
    float4 v = *reinterpret_cast<const float4*>(&src[rel]);
    ushort4 o = make_ushort4(f2bf(v.x), f2bf(v.y), f2bf(v.z), f2bf(v.w));
    *reinterpret_cast<ushort4*>(&dst[rel]) = o;
}

// ---------------------------------------------------------------------------
// bf16 MFMA NT GEMM: C = A[M,K]*B[N,K]^T, f32 out. 128x128 tile, BK=32,
// 4 waves (2x2 of 64x64), 16x16x32 MFMA. split-K via blocks_per_k (C0 gets
// per-kch plane offset); column-split dual output (C0 col<csplit, C1 else).
// EPI=1: v = softplus(v + bias[col]) fused epilogue (G3).
// ---------------------------------------------------------------------------
template<int EPI>
__global__ __launch_bounds__(256) void gemm_nt_bf16(
    const ushort* __restrict__ A, int lda,
    const ushort* __restrict__ B, int ldb,
    float* __restrict__ C0, float* __restrict__ C1, int csplit, int ldc,
    long cplane, int klen, int grid_n, int blocks_per_k,
    const float* __restrict__ bias)
{
    __shared__ ushort As[128 * 32];   // [row][32 bf16 = 64B rows], linear
    __shared__ ushort Bs[128 * 32];
    const int tid = threadIdx.x;
    const int wave = tid >> 6;
    const int lane = tid & 63;
    const int kch = blockIdx.x / blocks_per_k;
    const int rem = blockIdx.x % blocks_per_k;
    const int bm = (rem / grid_n) * 128;
    const int bn = (rem % grid_n) * 128;
    const int wm = (wave & 1) * 64;
    const int wn = (wave >> 1) * 64;
    const int koff = kch * klen;
    C0 += (long)kch * cplane;

    f32x4 acc[4][4] = {};

    const int offT = tid * 16;
    const char* Ab = (const char*)A;
    const char* Bb = (const char*)B;
    char* AsB = (char*)As;
    char* BsB = (char*)Bs;

    for (int k0 = 0; k0 < klen; k0 += 32) {
        __syncthreads();
        #pragma unroll
        for (int r = 0; r < 2; ++r) {
            int off = r * 4096 + offT;
            int row = off >> 6;
            int kb = off & 63;
            __builtin_amdgcn_global_load_lds(
                (const __attribute__((address_space(1))) void*)
                    (Ab + ((long)(bm + row) * lda + koff + k0) * 2 + kb),
                (__attribute__((address_space(3))) void*)
                    (AsB + r * 4096 + wave * 1024), 16, 0, 0);
            __builtin_amdgcn_global_load_lds(
                (const __attribute__((address_space(1))) void*)
                    (Bb + ((long)(bn + row) * ldb + koff + k0) * 2 + kb),
                (__attribute__((address_space(3))) void*)
                    (BsB + r * 4096 + wave * 1024), 16, 0, 0);
        }
        __syncthreads();

        bf16x8 af[4], bfr[4];
        #pragma unroll
        for (int i = 0; i < 4; ++i) {
            int ar = wm + i * 16 + (lane & 15);
            af[i]  = *reinterpret_cast<const bf16x8*>(AsB + ar * 64 + (lane >> 4) * 16);
            int br = wn + i * 16 + (lane & 15);
            bfr[i] = *reinterpret_cast<const bf16x8*>(BsB + br * 64 + (lane >> 4) * 16);
        }
        #pragma unroll
        for (int i = 0; i < 4; ++i)
            #pragma unroll
            for (int j = 0; j < 4; ++j)
                acc[i][j] = __builtin_amdgcn_mfma_f32_16x16x32_bf16(
                    af[i], bfr[j], acc[i][j], 0, 0, 0);
    }

    // C/D layout: col = lane&15, row = (lane>>4)*4 + q
    #pragma unroll
    for (int i = 0; i < 4; ++i) {
        int row0 = bm + wm + i * 16 + (lane >> 4) * 4;
        #pragma unroll
        for (int j = 0; j < 4; ++j) {
            int col = bn + wn + j * 16 + (lane & 15);
            float* Cp;
            int cc;
            if (col < csplit) { Cp = C0; cc = col; }
            else              { Cp = C1; cc = col - csplit; }
            float bv = (EPI == 1) ? bias[col] : 0.f;
            #pragma unroll
            for (int q = 0; q < 4; ++q) {
                float v = acc[i][j][q];
                if (EPI == 1) {
                    v += bv;
                    // stable softplus: max(v,0) + log1p(exp(-|v|))
                    v = fmaxf(v, 0.f) + log1pf(__expf(-fabsf(v)));
                }
                Cp[(long)(row0 + q) * ldc + cc] = v;
            }
        }
    }
}

// G4 reduce: out = sum of 4 partial planes, float4
__global__ __launch_bounds__(256) void g4_reduce(
    const float* __restrict__ Gp, float* __restrict__ out)
{
    long i4 = ((long)blockIdx.x * 256 + threadIdx.x) * 4;
    float4 a = *reinterpret_cast<const float4*>(&Gp[i4]);
    float4 b = *reinterpret_cast<const float4*>(&Gp[2097152 + i4]);
    float4 c = *reinterpret_cast<const float4*>(&Gp[4194304 + i4]);
    float4 d = *reinterpret_cast<const float4*>(&Gp[6291456 + i4]);
    float4 o = make_float4(a.x + b.x + c.x + d.x, a.y + b.y + c.y + d.y,
                           a.z + b.z + c.z + d.z, a.w + b.w + c.w + d.w);
    *reinterpret_cast<float4*>(&out[i4]) = o;
}

// G2 reduce: dbc = sum over SPLITK2 partial planes; also emit bf16 delta_r
// ([2048][64], cols 0..63) for the G3 MFMA.
__global__ __launch_bounds__(256) void gemm2_reduce(
    const float* __restrict__ Pb, float* __restrict__ dbc,
    ushort* __restrict__ dtr)
{
    int idx = blockIdx.x * 256 + threadIdx.x;   // 2048*96
    float s = 0.f;
    #pragma unroll
    for (int c = 0; c < SPLITK2; ++c) s += Pb[(long)c * LSEQ * DBCW + idx];
    dbc[idx] = s;
    int r = idx / DBCW;
    int c = idx - r * DBCW;
    if (c < RNK) dtr[r * RNK + c] = f2bf(s);
}

// ---------------------------------------------------------------------------
// Depthwise causal conv (K=4) + bias + SiLU. f32 in, bf16 out, 4 elems/thread.
// ---------------------------------------------------------------------------
__global__ __launch_bounds__(256) void conv_silu(
    const float* __restrict__ xr, const float* __restrict__ w,
    const float* __restrict__ b, ushort* __restrict__ xrc)
{
    int idx = blockIdx.x * 256 + threadIdx.x;   // l*512 + e4
    int l = idx >> 9;
    int e4 = (idx & 511) << 2;
    float4 zero = make_float4(0.f, 0.f, 0.f, 0.f);
    float4 r0 = (l >= 3) ? *reinterpret_cast<const float4*>(&xr[(long)(l - 3) * EDIM + e4]) : zero;
    float4 r1 = (l >= 2) ? *reinterpret_cast<const float4*>(&xr[(long)(l - 2) * EDIM + e4]) : zero;
    float4 r2 = (l >= 1) ? *reinterpret_cast<const float4*>(&xr[(long)(l - 1) * EDIM + e4]) : zero;
    float4 r3 = *reinterpret_cast<const float4*>(&xr[(long)l * EDIM + e4]);
    float4 bb = *reinterpret_cast<const float4*>(&b[e4]);
    float rr0[4] = {r0.x, r0.y, r0.z, r0.w};
    float rr1[4] = {r1.x, r1.y, r1.z, r1.w};
    float rr2[4] = {r2.x, r2.y, r2.z, r2.w};
    float rr3[4] = {r3.x, r3.y, r3.z, r3.w};
    float bbv[4] = {bb.x, bb.y, bb.z, bb.w};
    ushort o[4];
    #pragma unroll
    for (int j = 0; j < 4; ++j) {
        float4 wj = *reinterpret_cast<const float4*>(&w[(e4 + j) * 4]);
        float acc = bbv[j];
        acc = fmaf(wj.x, rr0[j], acc);
        acc = fmaf(wj.y, rr1[j], acc);
        acc = fmaf(wj.z, rr2[j], acc);
        acc = fmaf(wj.w, rr3[j], acc);
        o[j] = f2bf(acc / (1.f + __expf(-acc)));
    }
    *reinterpret_cast<ushort4*>(&xrc[(long)l * EDIM + e4]) =
        make_ushort4(o[0], o[1], o[2], o[3]);
}

// ---------------------------------------------------------------------------
// Selective scan. Phase A: local scan per (chunk, e), record decay product P
// and local final Hf. Layout [c][n][e].
// ---------------------------------------------------------------------------
__global__ __launch_bounds__(256) void scan_phaseA(
    const float* __restrict__ delta, const ushort* __restrict__ xr,
    const float* __restrict__ dbc, const float* __restrict__ A_log,
    float* __restrict__ P, float* __restrict__ Hf)
{
    int g = blockIdx.x * 256 + threadIdx.x;
    int e = g & (EDIM - 1);
    int c = g >> 11;
    float Aa[NS], h[NS], Pp[NS];
    #pragma unroll
    for (int n = 0; n < NS; ++n) {
        Aa[n] = -__expf(A_log[e * NS + n]);
        h[n] = 0.f;
        Pp[n] = 1.f;
    }
    int t0 = c * LC;
    for (int t = t0; t < t0 + LC; ++t) {
        float d  = delta[(long)t * EDIM + e];
        float xv = bf2f(xr[(long)t * EDIM + e]);
        const float* bm = dbc + (long)t * DBCW + RNK;
        float dx = d * xv;
        #pragma unroll
        for (int n = 0; n < NS; ++n) {
            float a = __expf(d * Aa[n]);
            h[n] = fmaf(a, h[n], dx * bm[n]);
            Pp[n] *= a;
        }
    }
    #pragma unroll
    for (int n = 0; n < NS; ++n) {
        P [(long)(c * NS + n) * EDIM + e] = Pp[n];
        Hf[(long)(c * NS + n) * EDIM + e] = h[n];
    }
}

// Phase B1: per (e,n,segment): within-segment prefix over 8 chunks.
__global__ __launch_bounds__(256) void scan_phaseB1(
    float* __restrict__ P, float* __restrict__ Hf,
    float* __restrict__ Sp, float* __restrict__ Sf)
{
    int gid = blockIdx.x * 256 + threadIdx.x;   // EDIM*NS*NSEG
    int e = gid & (EDIM - 1);
    int n = (gid >> 11) & (NS - 1);
    int g = gid >> 15;
    float h = 0.f, pp = 1.f;
    for (int c = g * NSEG; c < g * NSEG + NSEG; ++c) {
        long idx = (long)(c * NS + n) * EDIM + e;
        float p = P[idx];
        float f = Hf[idx];
        Hf[idx] = h;
        P[idx] = pp;
        h = fmaf(p, h, f);
        pp *= p;
    }
    long si = (long)(g * NS + n) * EDIM + e;
    Sp[si] = pp;
    Sf[si] = h;
}

// Phase B2: scan 8 segment summaries per (e,n); Sf[g] <- segment prefix h.
__global__ __launch_bounds__(256) void scan_phaseB2(
    const float* __restrict__ Sp, float* __restrict__ Sf)
{
    int gid = blockIdx.x * 256 + threadIdx.x;   // EDIM*NS
    int e = gid & (EDIM - 1);
    int n = gid >> 11;
    float h = 0.f;
    for (int g = 0; g < NSEG; ++g) {
        long idx = (long)(g * NS + n) * EDIM + e;
        float p = Sp[idx];
        float f = Sf[idx];
        Sf[idx] = h;
        h = fmaf(p, h, f);
    }
}

// Phase C: h_in(c) = P_within(c)*Sf(seg) + Hf_within(c); local scan with
// prefix; u = (y + D*x) * silu(z) -> bf16
__global__ __launch_bounds__(256) void scan_phaseC(
    const float* __restrict__ delta, const ushort* __restrict__ xr,
    const float* __restrict__ dbc, const float* __restrict__ A_log,
    const float* __restrict__ P, const float* __restrict__ Hf,
    const float* __restrict__ Sf, const float* __restrict__ Dp,
    const float* __restrict__ z, ushort* __restrict__ ubf)
{
    int gid = blockIdx.x * 256 + threadIdx.x;
    int e = gid & (EDIM - 1);
    int c = gid >> 11;
    int g = c >> 3;
    float Aa[NS], h[NS];
    #pragma unroll
    for (int n = 0; n < NS; ++n) {
        Aa[n] = -__expf(A_log[e * NS + n]);
        long ci = (long)(c * NS + n) * EDIM + e;
        long si = (long)(g * NS + n) * EDIM + e;
        h[n] = fmaf(P[ci], Sf[si], Hf[ci]);
    }
    float dD = Dp[e];
    int t0 = c * LC;
    for (int t = t0; t < t0 + LC; ++t) {
        float d  = delta[(long)t * EDIM + e];
        float xv = bf2f(xr[(long)t * EDIM + e]);
        const float* bm = dbc + (long)t * DBCW + RNK;
        const float* cm = dbc + (long)t * DBCW + RNK + NS;
        float dx = d * xv;
        float y = 0.f;
        #pragma unroll
        for (int n = 0; n < NS; ++n) {
            float a = __expf(d * Aa[n]);
            h[n] = fmaf(a, h[n], dx * bm[n]);
            y = fmaf(h[n], cm[n], y);
        }
        y = fmaf(dD, xv, y);
        float zv = z[(long)t * EDIM + e];
        float sz = zv / (1.f + __expf(-zv));
        ubf[(long)t * EDIM + e] = f2bf(y * sz);
    }
}

// ---------------------------------------------------------------------------
extern "C" void kernel_launch(void* const* d_in, const int* in_sizes, int n_in,
                              void* d_out, int out_size, void* d_ws, size_t ws_size,
                              hipStream_t stream) {
    const float* x         = (const float*)d_in[0];
    const float* in_proj_w = (const float*)d_in[1];
    const float* conv_w    = (const float*)d_in[2];
    const float* conv_b    = (const float*)d_in[3];
    const float* x_proj_w  = (const float*)d_in[4];
    const float* dt_proj_w = (const float*)d_in[5];
    const float* dt_proj_b = (const float*)d_in[6];
    const float* A_log     = (const float*)d_in[7];
    const float* Dp        = (const float*)d_in[8];
    const float* out_proj_w= (const float*)d_in[9];
    float* out = (float*)d_out;

    float* ws = (float*)d_ws;
    const long M1 = 1048576;
    // [0,1M): xbf ; [1M,3M): w1bf  -> dead after G1; Pb = [0,3M);
    //   after gemm2_reduce Pb dead; ubf = [0,2M) (4M ushort)
    ushort* xbf     = (ushort*)ws;
    ushort* w1bf    = (ushort*)(ws + 1 * M1);
    float*  Pb      = ws;
    ushort* ubf     = (ushort*)ws;
    // [3M, 3.0625M): junk C1 for G2 cols 96..127
    float*  junk    = ws + 3 * M1;
    // [3.25M, 3.375M): xpw_pad (128x2048 bf16)
    ushort* xpw_pad = (ushort*)(ws + 3 * M1 + M1 / 4);
    // [3.5M, 4.5M): w4bf
    ushort* w4bf    = (ushort*)(ws + 3 * M1 + M1 / 2);
    // [4.5M, 8.5M): xr_f32; dead after conv -> delta overlays
    float*  xr_f32  = ws + 4 * M1 + M1 / 2;
    float*  delta   = xr_f32;
    // [8.5M, 12.5M): z_f32; after scanC both delta and z are dead ->
    //   Gp (4 planes, 8M f32) overlays [4.5M, 12.5M)
    float*  z_f32   = ws + 8 * M1 + M1 / 2;
    float*  Gp      = ws + 4 * M1 + M1 / 2;
    // [12.5M, 14.5M): xrcbf (4M ushort)
    ushort* xrcbf   = (ushort*)(ws + 12 * M1 + M1 / 2);
    // [14.5M, 16.5M): P ; [16.5M, 18.5M): Hf
    float*  P       = ws + 14 * M1 + M1 / 2;
    float*  Hf      = ws + 16 * M1 + M1 / 2;
    // [18.5M, 18.75M): Sp ; [18.75M, 19M): Sf
    float*  Sp      = ws + 18 * M1 + M1 / 2;
    float*  Sf      = ws + 18 * M1 + 3 * M1 / 4;
    // [19M, ...): dbc (196608 f32), w3bf (131072 us), dtr_bf (131072 us)
    float*  dbc     = ws + 19 * M1;
    ushort* w3bf    = (ushort*)(ws + 19 * M1 + 196608);
    ushort* dtr_bf  = (ushort*)(ws + 19 * M1 + 196608 + 65536);

    dim3 blk(256);

    // prep: casts + x_proj_w pad
    prep_all<<<(R5 / 4 + 255) / 256, blk, 0, stream>>>(
        x, in_proj_w, out_proj_w, x_proj_w, dt_proj_w,
        xbf, w1bf, w4bf, xpw_pad, w3bf);

    // G1: [xr|z](f32 planes) = x @ in_proj_w^T   [2048,4096] k=1024
    gemm_nt_bf16<0><<<512, blk, 0, stream>>>(
        xbf, DM, w1bf, DM, xr_f32, z_f32, EDIM, EDIM, 0, DM, 32, 512, nullptr);

    // conv + silu: xr_f32 -> xrcbf (bf16)
    conv_silu<<<(LSEQ * EDIM) / 1024, blk, 0, stream>>>(xr_f32, conv_w, conv_b, xrcbf);

    // G2: Pb[kch] = xrcbf[:, kch*128:+128] @ xpw_pad^T  (MFMA, split-K x16)
    gemm_nt_bf16<0><<<SPLITK2 * 16, blk, 0, stream>>>(
        xrcbf, EDIM, xpw_pad, EDIM, Pb, junk, DBCW, DBCW,
        (long)LSEQ * DBCW, EDIM / SPLITK2, 1, 16, nullptr);
    gemm2_reduce<<<(LSEQ * DBCW) / 256, blk, 0, stream>>>(Pb, dbc, dtr_bf);

    // G3: delta = softplus(delta_r @ dt_proj_w^T + b)  [2048,2048] k=64 (MFMA)
    gemm_nt_bf16<1><<<256, blk, 0, stream>>>(
        dtr_bf, RNK, w3bf, RNK, delta, junk, 1 << 30, EDIM, 0, RNK, 16, 256,
        dt_proj_b);

    // scan
    scan_phaseA<<<(NCH * EDIM) / 256, blk, 0, stream>>>(
        delta, xrcbf, dbc, A_log, P, Hf);
    scan_phaseB1<<<(EDIM * NS * NSEG) / 256, blk, 0, stream>>>(P, Hf, Sp, Sf);
    scan_phaseB2<<<(EDIM * NS) / 256, blk, 0, stream>>>(Sp, Sf);
    scan_phaseC<<<(NCH * EDIM) / 256, blk, 0, stream>>>(
        delta, xrcbf, dbc, A_log, P, Hf, Sf, Dp, z_f32, ubf);

    // G4: Gp[kch] = u @ out_proj_w^T  [2048,1024] k=2048, split-K x4
    gemm_nt_bf16<0><<<SPLITK4 * 128, blk, 0, stream>>>(
        ubf, EDIM, w4bf, EDIM, Gp, junk, 1 << 30, DM,
        (long)LSEQ * DM, EDIM / SPLITK4, 8, 128, nullptr);
    g4_reduce<<<(LSEQ * DM) / 1024, blk, 0, stream>>>(Gp, out);
}